// Round 16
// baseline (258.247 us; speedup 1.0000x reference)
//
#include <hip/hip_runtime.h>
#include <hip/hip_bf16.h>

typedef __attribute__((ext_vector_type(4))) float  f32x4;
typedef __attribute__((ext_vector_type(8))) short  short8;
typedef __attribute__((ext_vector_type(2))) float  flt2;
typedef long long ll;

__device__ __forceinline__ short f2bf(float f) {
    __hip_bfloat16 h = __float2bfloat16(f);
    short s; __builtin_memcpy(&s, &h, 2);
    return s;
}
__device__ __forceinline__ float bf2f(short s) {
    unsigned u = ((unsigned)(unsigned short)s) << 16;
    float f; __builtin_memcpy(&f, &u, 4);
    return f;
}
__device__ __forceinline__ void gload_lds16(const void* g, void* l) {
    __builtin_amdgcn_global_load_lds(
        (const __attribute__((address_space(1))) unsigned*)(g),
        (__attribute__((address_space(3))) unsigned*)(l),
        16, 0, 0);
}
// bijective XCD swizzle (m204)
__device__ __forceinline__ int xcd_swz(int bid, int nwg) {
    int q8 = nwg >> 3, r8 = nwg & 7;
    int xcd = bid & 7, j = bid >> 3;
    return (xcd < r8 ? xcd * (q8 + 1) : r8 * (q8 + 1) + (xcd - r8) * q8) + j;
}

// ---------------------------------------------------------------------------
// prep: weights -> bf16 [k][co][ci]; W2t/W3t padded to 28 k-tiles (tile 27 = 0)
// ---------------------------------------------------------------------------
__global__ void prep_kernel(const float* __restrict__ W1, const float* __restrict__ W2,
                            const float* __restrict__ W3, const float* __restrict__ W4,
                            const float* __restrict__ W5,
                            short* W1t, short* W2t, short* W3t, short* W4t, short* W5t) {
    int gid = blockIdx.x * 256 + threadIdx.x;
    if (gid < 32 * 64) {
        int co = gid >> 6, e = gid & 63;
        float v = 0.f;
        if (e < 54) { int k = e >> 1, ci = e & 1; v = W1[(k * 2 + ci) * 32 + co]; }
        W1t[gid] = f2bf(v);
        return;
    }
    int g = gid - 32 * 64;
    if (g < 28 * 2048) { int k = g / 2048, r = g % 2048, co = r >> 5, ci = r & 31;
        W2t[g] = (k < 27) ? f2bf(W2[((ll)k * 32 + ci) * 64 + co]) : (short)0; return; }
    g -= 28 * 2048;
    if (g < 28 * 8192) { int k = g / 8192, r = g % 8192, co = r >> 6, ci = r & 63;
        W3t[g] = (k < 27) ? f2bf(W3[((ll)k * 64 + ci) * 128 + co]) : (short)0; return; }
    g -= 28 * 8192;
    if (g < 8 * 64 * 128) { int k = g / (64*128), r = g % (64*128), co = r >> 7, ci = r & 127;
        W4t[g] = f2bf(W4[((ll)k * 128 + ci) * 64 + co]); return; }
    g -= 8 * 64 * 128;
    if (g < 8 * 32 * 64) { int k = g / (32*64), r = g % (32*64), co = r >> 6, ci = r & 63;
        W5t[g] = f2bf(W5[((ll)k * 64 + ci) * 32 + co]); return; }
}

// ---------------------------------------------------------------------------
// conv1 as dense MFMA GEMM + fused stats partials
// ---------------------------------------------------------------------------
__launch_bounds__(256)
__global__ void c1_kernel(const float* __restrict__ feats, const int* __restrict__ nbr,
                          const short* __restrict__ W1t, short* __restrict__ out,
                          float* __restrict__ part, int N) {
    __shared__ float sc[8 * 32];
    const int wgid = xcd_swz(blockIdx.x, gridDim.x);
    int tid = threadIdx.x, lane = tid & 63, wave = tid >> 6;
    int rb = wgid * 64 + wave * 16;
    int r = rb + (lane & 15);
    int rl = r < N ? r : N - 1;
    int seg = lane >> 4, l15 = lane & 15;
    f32x4 acc[2];
    acc[0] = (f32x4){0,0,0,0}; acc[1] = (f32x4){0,0,0,0};
    short8 a[2];
    #pragma unroll
    for (int kc = 0; kc < 2; ++kc) {
        #pragma unroll
        for (int j = 0; j < 4; ++j) {
            int k = kc * 16 + seg * 4 + j;
            flt2 f = (flt2){0.f, 0.f};
            if (k < 27) {
                int idx = nbr[(ll)k * N + rl];
                if (idx >= 0) f = *(const flt2*)(feats + 2 * (ll)idx);
            }
            a[kc][2*j]   = f2bf(f[0]);
            a[kc][2*j+1] = f2bf(f[1]);
        }
    }
    #pragma unroll
    for (int kc = 0; kc < 2; ++kc)
        #pragma unroll
        for (int c = 0; c < 2; ++c) {
            short8 b = *(const short8*)(W1t + (c*16 + l15) * 64 + kc * 32 + seg * 8);
            acc[c] = __builtin_amdgcn_mfma_f32_16x16x32_bf16(a[kc], b, acc[c], 0, 0, 0);
        }
    int r0 = rb + seg * 4;
    #pragma unroll
    for (int c = 0; c < 2; ++c) {
        int col = c * 16 + l15;
        #pragma unroll
        for (int j = 0; j < 4; ++j)
            if (r0 + j < N) out[(ll)(r0 + j) * 32 + col] = f2bf(acc[c][j]);
    }
    float s[2], q[2];
    #pragma unroll
    for (int c = 0; c < 2; ++c) { s[c] = 0.f; q[c] = 0.f; }
    #pragma unroll
    for (int c = 0; c < 2; ++c)
        #pragma unroll
        for (int j = 0; j < 4; ++j) {
            float v = (r0 + j < N) ? acc[c][j] : 0.f;
            s[c] += v; q[c] += v * v;
        }
    #pragma unroll
    for (int c = 0; c < 2; ++c) {
        s[c] += __shfl_xor(s[c], 16); q[c] += __shfl_xor(q[c], 16);
        s[c] += __shfl_xor(s[c], 32); q[c] += __shfl_xor(q[c], 32);
    }
    if (lane < 16) {
        #pragma unroll
        for (int c = 0; c < 2; ++c) {
            sc[(wave * 2 + 0) * 32 + c * 16 + l15] = s[c];
            sc[(wave * 2 + 1) * 32 + c * 16 + l15] = q[c];
        }
    }
    __syncthreads();
    for (int i = tid; i < 32; i += 256) {
        float ss = sc[0*32+i] + sc[2*32+i] + sc[4*32+i] + sc[6*32+i];
        float qq = sc[1*32+i] + sc[3*32+i] + sc[5*32+i] + sc[7*32+i];
        part[(ll)wgid * 64 + i]      = ss;
        part[(ll)wgid * 64 + 32 + i] = qq;
    }
}

// ---------------------------------------------------------------------------
// L2 conv (32->64) BARRIER-FREE: ALL 27 weight tiles staged in LDS once
// (108 KB, 1 block/CU), then fully-unrolled k-loop with 8-deep register
// A-prefetch ring. No per-k barriers/waitcnts — compiler free-schedules.
// Fused stats. XCD swizzle.
// ---------------------------------------------------------------------------
__launch_bounds__(256, 1)
__global__ void msL2full_kernel(const short* __restrict__ inb, const int* __restrict__ nbr,
                                const short* __restrict__ Wt, short* __restrict__ out,
                                float* __restrict__ part, int N, int zoff) {
    constexpr int RG = 2;                          // 32 rows per wave, 128/block
    __shared__ __align__(16) short lb[27 * 2048];  // 27 tiles x 64co x 32ci

    const int wgid = xcd_swz(blockIdx.x, gridDim.x);
    const int tid = threadIdx.x, lane = tid & 63, wave = tid >> 6;
    const int seg = lane >> 4, l15 = lane & 15;
    const int wrb = wgid * 128 + wave * 32;
    const char* inB = (const char*)inb;

    int rl[RG];
    #pragma unroll
    for (int rg = 0; rg < RG; ++rg) {
        int r = wrb + rg * 16 + l15;
        rl[rg] = r < N ? r : N - 1;
    }

    // stage ALL weights: tile it, chunk tid (write (sg*64+co)*8 = tid*8)
    {
        int co = tid & 63, sg = tid >> 6;
        #pragma unroll
        for (int it = 0; it < 27; ++it)
            gload_lds16(Wt + (ll)it * 2048 + co * 32 + sg * 8, &lb[it * 2048 + tid * 8]);
    }

    // all 27 gather byte-offsets (1 wave/SIMD -> huge VGPR budget, no spill)
    int off[27][RG];
    #pragma unroll
    for (int k = 0; k < 27; ++k)
        #pragma unroll
        for (int rg = 0; rg < RG; ++rg) {
            int idx = nbr[(ll)k * N + rl[rg]];
            off[k][rg] = (idx >= 0) ? (idx << 6) : zoff;
        }

    auto ldA = [&](short8 (&a)[RG], const int (&o)[RG]) {
        #pragma unroll
        for (int rg = 0; rg < RG; ++rg)
            a[rg] = *(const short8*)(inB + o[rg] + seg * 16);
    };

    // prime 8-deep ring
    short8 aR[8][RG];
    #pragma unroll
    for (int p = 0; p < 8; ++p) ldA(aR[p], off[p]);

    asm volatile("s_waitcnt vmcnt(0) lgkmcnt(0)" ::: "memory");
    __builtin_amdgcn_s_barrier();          // LDS weights ready (once)

    f32x4 acc[RG][4];
    #pragma unroll
    for (int rg = 0; rg < RG; ++rg)
        #pragma unroll
        for (int c = 0; c < 4; ++c) acc[rg][c] = (f32x4){0.f, 0.f, 0.f, 0.f};

    #pragma unroll
    for (int k = 0; k < 27; ++k) {
        #pragma unroll
        for (int c = 0; c < 4; ++c) {
            short8 b = *(const short8*)&lb[k * 2048 + (seg * 64 + c * 16 + l15) * 8];
            #pragma unroll
            for (int rg = 0; rg < RG; ++rg)
                acc[rg][c] = __builtin_amdgcn_mfma_f32_16x16x32_bf16(
                    aR[k & 7][rg], b, acc[rg][c], 0, 0, 0);
        }
        if (k + 8 < 27) ldA(aR[k & 7], off[k + 8]);
    }

    // C-write
    #pragma unroll
    for (int rg = 0; rg < RG; ++rg)
        #pragma unroll
        for (int c = 0; c < 4; ++c) {
            int col = c * 16 + l15;
            #pragma unroll
            for (int j = 0; j < 4; ++j) {
                int rr = wrb + rg * 16 + seg * 4 + j;
                if (rr < N) out[(ll)rr * 64 + col] = f2bf(acc[rg][c][j]);
            }
        }

    // fused stats partials
    float s[4], q[4];
    #pragma unroll
    for (int c = 0; c < 4; ++c) { s[c] = 0.f; q[c] = 0.f; }
    #pragma unroll
    for (int rg = 0; rg < RG; ++rg)
        #pragma unroll
        for (int c = 0; c < 4; ++c)
            #pragma unroll
            for (int j = 0; j < 4; ++j) {
                int rr = wrb + rg * 16 + seg * 4 + j;
                float v = (rr < N) ? acc[rg][c][j] : 0.f;
                s[c] += v; q[c] += v * v;
            }
    #pragma unroll
    for (int c = 0; c < 4; ++c) {
        s[c] += __shfl_xor(s[c], 16); q[c] += __shfl_xor(q[c], 16);
        s[c] += __shfl_xor(s[c], 32); q[c] += __shfl_xor(q[c], 32);
    }
    __syncthreads();
    float* sc = (float*)&lb[0];
    if (lane < 16) {
        #pragma unroll
        for (int c = 0; c < 4; ++c) {
            sc[(wave * 2 + 0) * 64 + c * 16 + l15] = s[c];
            sc[(wave * 2 + 1) * 64 + c * 16 + l15] = q[c];
        }
    }
    __syncthreads();
    for (int i = tid; i < 64; i += 256) {
        float ss = sc[0*64+i] + sc[2*64+i] + sc[4*64+i] + sc[6*64+i];
        float qq = sc[1*64+i] + sc[3*64+i] + sc[5*64+i] + sc[7*64+i];
        part[(ll)wgid * 128 + i]      = ss;
        part[(ll)wgid * 128 + 64 + i] = qq;
    }
}

// ---------------------------------------------------------------------------
// Sparse MFMA conv v7 (R13-verified) — used for L3.
// ---------------------------------------------------------------------------
template<int CIN, int COLS, int RG, int MINW>
__launch_bounds__(256, MINW)
__global__ void msconv7_kernel(const short* __restrict__ inb, const int* __restrict__ nbr,
                               const short* __restrict__ Wt, short* __restrict__ out,
                               float* __restrict__ part, int N, int zoff) {
    constexpr int KC = CIN / 32, NT = COLS / 16;
    constexpr int CPK = COLS * CIN / 8, BIT = CPK / 256;
    constexpr int WST = COLS * CIN;
    constexpr int SH = (CIN == 32) ? 6 : 7;
    __shared__ __align__(16) short lb[2][WST];

    const int wgid = xcd_swz(blockIdx.x, gridDim.x);
    const int tid = threadIdx.x, lane = tid & 63, wave = tid >> 6;
    const int seg = lane >> 4, l15 = lane & 15;
    const int wrb = wgid * (64 * RG) + wave * (16 * RG);
    const char* inB = (const char*)inb;

    int rl[RG];
    #pragma unroll
    for (int rg = 0; rg < RG; ++rg) {
        int r = wrb + rg * 16 + l15;
        rl[rg] = r < N ? r : N - 1;
    }

    auto rawIdx = [&](int k, int (&ix)[RG]) {
        #pragma unroll
        for (int rg = 0; rg < RG; ++rg) ix[rg] = nbr[(ll)k * N + rl[rg]];
    };
    auto mkoff = [&](const int (&ix)[RG], int (&o)[RG]) {
        #pragma unroll
        for (int rg = 0; rg < RG; ++rg) o[rg] = (ix[rg] >= 0) ? (ix[rg] << SH) : zoff;
    };
    auto stage = [&](int kn, int buf) {
        #pragma unroll
        for (int it = 0; it < BIT; ++it) {
            int q = it * 256 + tid;
            int co = q % COLS, sg = (q / COLS) & 3, kc = q / (COLS * 4);
            gload_lds16(Wt + (ll)kn * WST + co * CIN + kc * 32 + sg * 8, &lb[buf][q * 8]);
        }
    };
    auto ldA = [&](short8 (&a)[RG][KC], const int (&o)[RG]) {
        #pragma unroll
        for (int rg = 0; rg < RG; ++rg) {
            const char* base = inB + o[rg];
            #pragma unroll
            for (int kc = 0; kc < KC; ++kc)
                a[rg][kc] = *(const short8*)(base + kc * 64 + seg * 16);
        }
    };

    f32x4 acc[RG][NT];
    #pragma unroll
    for (int rg = 0; rg < RG; ++rg)
        #pragma unroll
        for (int c = 0; c < NT; ++c) acc[rg][c] = (f32x4){0.f, 0.f, 0.f, 0.f};

    auto compute = [&](int buf, short8 (&a)[RG][KC]) {
        #pragma unroll
        for (int kc = 0; kc < KC; ++kc)
            #pragma unroll
            for (int c = 0; c < NT; ++c) {
                short8 b = *(const short8*)&lb[buf][((kc * 4 + seg) * COLS + c * 16 + l15) * 8];
                #pragma unroll
                for (int rg = 0; rg < RG; ++rg)
                    acc[rg][c] = __builtin_amdgcn_mfma_f32_16x16x32_bf16(
                        a[rg][kc], b, acc[rg][c], 0, 0, 0);
            }
    };

    short8 aA[RG][KC], aB[RG][KC];
    int iF[RG], offC[RG];

    {
        int i0[RG], i1[RG], o0[RG];
        rawIdx(0, i0); rawIdx(1, i1); rawIdx(2, iF);
        mkoff(i0, o0); mkoff(i1, offC);
        stage(0, 0);
        __builtin_amdgcn_sched_barrier(0);
        ldA(aA, o0);
        __builtin_amdgcn_sched_barrier(0);
        asm volatile("s_waitcnt vmcnt(%0) lgkmcnt(0)" :: "n"(RG * KC) : "memory");
        __builtin_amdgcn_s_barrier();
        __builtin_amdgcn_sched_barrier(0);
    }

    #pragma unroll
    for (int k = 0; k < 27; ++k) {
        int iN[RG];
        if (k + 1 < 27) {
            if (k + 3 < 27) rawIdx(k + 3, iN);
            __builtin_amdgcn_sched_barrier(0);
            stage(k + 1, (k + 1) & 1);
            __builtin_amdgcn_sched_barrier(0);
            if (k & 1) ldA(aA, offC); else ldA(aB, offC);
            __builtin_amdgcn_sched_barrier(0);
        }
        if (k & 1) compute(1, aB); else compute(0, aA);
        if (k + 1 < 27) {
            __builtin_amdgcn_sched_barrier(0);
            asm volatile("s_waitcnt vmcnt(%0) lgkmcnt(0)" :: "n"(RG * KC) : "memory");
            __builtin_amdgcn_s_barrier();
            __builtin_amdgcn_sched_barrier(0);
            mkoff(iF, offC);
            if (k + 3 < 27) {
                #pragma unroll
                for (int rg = 0; rg < RG; ++rg) iF[rg] = iN[rg];
            }
        }
    }

    #pragma unroll
    for (int rg = 0; rg < RG; ++rg)
        #pragma unroll
        for (int c = 0; c < NT; ++c) {
            int col = c * 16 + l15;
            #pragma unroll
            for (int j = 0; j < 4; ++j) {
                int rr = wrb + rg * 16 + seg * 4 + j;
                if (rr < N) out[(ll)rr * COLS + col] = f2bf(acc[rg][c][j]);
            }
        }

    float s[NT], q[NT];
    #pragma unroll
    for (int c = 0; c < NT; ++c) { s[c] = 0.f; q[c] = 0.f; }
    #pragma unroll
    for (int rg = 0; rg < RG; ++rg)
        #pragma unroll
        for (int c = 0; c < NT; ++c)
            #pragma unroll
            for (int j = 0; j < 4; ++j) {
                int rr = wrb + rg * 16 + seg * 4 + j;
                float v = (rr < N) ? acc[rg][c][j] : 0.f;
                s[c] += v; q[c] += v * v;
            }
    #pragma unroll
    for (int c = 0; c < NT; ++c) {
        s[c] += __shfl_xor(s[c], 16); q[c] += __shfl_xor(q[c], 16);
        s[c] += __shfl_xor(s[c], 32); q[c] += __shfl_xor(q[c], 32);
    }
    __syncthreads();
    float* sc = (float*)&lb[0][0];
    if (lane < 16) {
        #pragma unroll
        for (int c = 0; c < NT; ++c) {
            sc[(wave * 2 + 0) * COLS + c * 16 + l15] = s[c];
            sc[(wave * 2 + 1) * COLS + c * 16 + l15] = q[c];
        }
    }
    __syncthreads();
    for (int i = tid; i < COLS; i += 256) {
        float ss = sc[0*COLS+i] + sc[2*COLS+i] + sc[4*COLS+i] + sc[6*COLS+i];
        float qq = sc[1*COLS+i] + sc[3*COLS+i] + sc[5*COLS+i] + sc[7*COLS+i];
        part[(ll)wgid * 2 * COLS + i]        = ss;
        part[(ll)wgid * 2 * COLS + COLS + i] = qq;
    }
}

// ---------------------------------------------------------------------------
// Decoder list build (merged)
// ---------------------------------------------------------------------------
__global__ void dcountB_kernel(const int* __restrict__ poffA, int NA, int* __restrict__ cntA,
                               const int* __restrict__ poffB, int NB, int* __restrict__ cntB) {
    const int* poff = blockIdx.y ? poffB : poffA;
    int* cnt = blockIdx.y ? cntB : cntA;
    int N = blockIdx.y ? NB : NA;
    __shared__ int lc[8];
    if (threadIdx.x < 8) lc[threadIdx.x] = 0;
    __syncthreads();
    int r = blockIdx.x * 256 + threadIdx.x;
    if (r < N) atomicAdd(&lc[poff[r]], 1);
    __syncthreads();
    if (threadIdx.x < 8 && lc[threadIdx.x]) atomicAdd(&cnt[threadIdx.x], lc[threadIdx.x]);
}

__global__ void dprefixB_kernel(const int* __restrict__ cntA, int* basesA, int* kofbA,
                                int* permA, int nblkA,
                                const int* __restrict__ cntB, int* basesB, int* kofbB,
                                int* permB, int nblkB) {
    const int* cnt = blockIdx.x ? cntB : cntA;
    int* bases = blockIdx.x ? basesB : basesA;
    int* kofb  = blockIdx.x ? kofbB  : kofbA;
    int* perm  = blockIdx.x ? permB  : permA;
    int nblk   = blockIdx.x ? nblkB  : nblkA;
    __shared__ int base[9];
    if (threadIdx.x == 0) {
        int b = 0;
        for (int k = 0; k < 8; ++k) { base[k] = b; b += (cnt[k] + 63) & ~63; }
        base[8] = b;
        for (int k = 0; k < 9; ++k) bases[k] = base[k];
    }
    __syncthreads();
    int nb = base[8] >> 6;
    for (int i = threadIdx.x; i < nblk; i += 256) {
        int k = -1;
        if (i < nb) {
            int rb = i << 6; k = 0;
            while (rb >= base[k + 1]) ++k;
        }
        kofb[i] = k;
    }
    for (int k = 0; k < 8; ++k) {
        int s = base[k] + cnt[k], e = base[k + 1];
        for (int i = s + threadIdx.x; i < e; i += 256) perm[i] = -1;
    }
}

__global__ void dscatterB_kernel(const int* __restrict__ poffA, const int* basesA,
                                 int* curA, int* permA, int NA,
                                 const int* __restrict__ poffB, const int* basesB,
                                 int* curB, int* permB, int NB) {
    const int* poff = blockIdx.y ? poffB : poffA;
    const int* bases = blockIdx.y ? basesB : basesA;
    int* curp = blockIdx.y ? curB : curA;
    int* perm = blockIdx.y ? permB : permA;
    int N = blockIdx.y ? NB : NA;
    __shared__ int lc[8], lbs[8];
    if (threadIdx.x < 8) lc[threadIdx.x] = 0;
    __syncthreads();
    int r = blockIdx.x * 256 + threadIdx.x;
    int k = 0, myl = 0;
    if (r < N) { k = poff[r]; myl = atomicAdd(&lc[k], 1); }
    __syncthreads();
    if (threadIdx.x < 8) lbs[threadIdx.x] = atomicAdd(&curp[threadIdx.x], lc[threadIdx.x]);
    __syncthreads();
    if (r < N) perm[bases[k] + lbs[k] + myl] = r;
}

// ---------------------------------------------------------------------------
// Decoder gather-GEMM: inline BN+ReLU (once/row, prologue) + stats + swizzle
// ---------------------------------------------------------------------------
template<int CIN, int COUT>
__launch_bounds__(256)
__global__ void gdec_kernel(const short* __restrict__ inb, const int* __restrict__ perm,
                            const int* __restrict__ kofb, const int* __restrict__ pidx,
                            const short* __restrict__ Wt,
                            const float* __restrict__ Abn, const float* __restrict__ Bbn,
                            short* __restrict__ out, float* __restrict__ part) {
    constexpr int KC = CIN / 32, NT = COUT / 16;
    constexpr int CPK = COUT * CIN / 8, BIT = CPK / 256;
    __shared__ __align__(16) short lb[COUT * CIN];
    const int wgid = xcd_swz(blockIdx.x, gridDim.x);
    const int tid = threadIdx.x, lane = tid & 63, wave = tid >> 6;
    int k = kofb[wgid];
    if (k < 0) {
        for (int i = tid; i < 2 * COUT; i += 256) part[(ll)wgid * 2 * COUT + i] = 0.f;
        return;
    }
    const int seg = lane >> 4, l15 = lane & 15;
    const int wrb = wgid * 64 + wave * 16;
    int rl = wrb + l15;
    int pr = perm[rl];
    int idx = pr < 0 ? -1 : pidx[pr];
    int valid = (idx >= 0);

    #pragma unroll
    for (int it = 0; it < BIT; ++it) {
        int q = it * 256 + tid;
        int co = q % COUT, sg = (q / COUT) & 3, kc = q / (COUT * 4);
        gload_lds16(Wt + ((ll)k * COUT + co) * CIN + kc * 32 + sg * 8, &lb[q * 8]);
    }
    f32x4 cA[KC][2], cB[KC][2];
    #pragma unroll
    for (int kc = 0; kc < KC; ++kc) {
        cA[kc][0] = *(const f32x4*)(Abn + kc * 32 + seg * 8);
        cA[kc][1] = *(const f32x4*)(Abn + kc * 32 + seg * 8 + 4);
        cB[kc][0] = *(const f32x4*)(Bbn + kc * 32 + seg * 8);
        cB[kc][1] = *(const f32x4*)(Bbn + kc * 32 + seg * 8 + 4);
    }
    short8 a[KC];
    const short* base = inb + (ll)(idx < 0 ? 0 : idx) * CIN;
    #pragma unroll
    for (int kc = 0; kc < KC; ++kc) {
        short8 raw = *(const short8*)(base + kc * 32 + seg * 8);
        #pragma unroll
        for (int j = 0; j < 8; ++j) {
            float x = bf2f(raw[j]);
            float y = fmaf(x, cA[kc][j >> 2][j & 3], cB[kc][j >> 2][j & 3]);
            y = y > 0.f ? y : 0.f;
            a[kc][j] = valid ? f2bf(y) : (short)0;
        }
    }

    f32x4 acc[NT];
    #pragma unroll
    for (int c = 0; c < NT; ++c) acc[c] = (f32x4){0.f, 0.f, 0.f, 0.f};
    __syncthreads();
    #pragma unroll
    for (int kc = 0; kc < KC; ++kc)
        #pragma unroll
        for (int c = 0; c < NT; ++c) {
            short8 b = *(const short8*)&lb[((kc * 4 + seg) * COUT + c * 16 + l15) * 8];
            acc[c] = __builtin_amdgcn_mfma_f32_16x16x32_bf16(a[kc], b, acc[c], 0, 0, 0);
        }
    #pragma unroll
    for (int j = 0; j < 4; ++j) {
        int prs = __shfl(pr, seg * 4 + j, 64);
        if (prs >= 0) {
            #pragma unroll
            for (int c = 0; c < NT; ++c)
                out[(ll)prs * COUT + c * 16 + l15] = f2bf(acc[c][j]);
        }
    }
    float s[NT], q[NT];
    #pragma unroll
    for (int c = 0; c < NT; ++c) { s[c] = 0.f; q[c] = 0.f; }
    #pragma unroll
    for (int c = 0; c < NT; ++c)
        #pragma unroll
        for (int j = 0; j < 4; ++j) { float v = acc[c][j]; s[c] += v; q[c] += v * v; }
    #pragma unroll
    for (int c = 0; c < NT; ++c) {
        s[c] += __shfl_xor(s[c], 16); q[c] += __shfl_xor(q[c], 16);
        s[c] += __shfl_xor(s[c], 32); q[c] += __shfl_xor(q[c], 32);
    }
    __syncthreads();
    float* sc = (float*)lb;
    if (lane < 16) {
        #pragma unroll
        for (int c = 0; c < NT; ++c) {
            sc[(wave * 2 + 0) * COUT + c * 16 + l15] = s[c];
            sc[(wave * 2 + 1) * COUT + c * 16 + l15] = q[c];
        }
    }
    __syncthreads();
    for (int i = tid; i < COUT; i += 256) {
        float ss = sc[0*COUT+i] + sc[2*COUT+i] + sc[4*COUT+i] + sc[6*COUT+i];
        float qq = sc[1*COUT+i] + sc[3*COUT+i] + sc[5*COUT+i] + sc[7*COUT+i];
        part[(ll)wgid * 2 * COUT + i]        = ss;
        part[(ll)wgid * 2 * COUT + COUT + i] = qq;
    }
}

// ---------------------------------------------------------------------------
// red2 / bnrelu / outk
// ---------------------------------------------------------------------------
__global__ void red2_kernel(const float* __restrict__ part, int nblk,
                            const float* __restrict__ g, const float* __restrict__ bb,
                            float* __restrict__ A, float* __restrict__ B, int C, int N) {
    int c = blockIdx.x;
    float s = 0.f, q = 0.f;
    for (int i = threadIdx.x; i < nblk; i += 256) {
        s += part[(ll)i * 2 * C + c];
        q += part[(ll)i * 2 * C + C + c];
    }
    __shared__ float ls[256], lq[256];
    ls[threadIdx.x] = s; lq[threadIdx.x] = q;
    __syncthreads();
    for (int str = 128; str >= 1; str >>= 1) {
        if (threadIdx.x < str) {
            ls[threadIdx.x] += ls[threadIdx.x + str];
            lq[threadIdx.x] += lq[threadIdx.x + str];
        }
        __syncthreads();
    }
    if (threadIdx.x == 0) {
        float inv = 1.0f / (float)N;
        float mu = ls[0] * inv, var = lq[0] * inv - mu * mu;
        float a = g[c] * rsqrtf(var + 1e-5f);
        A[c] = a; B[c] = bb[c] - mu * a;
    }
}

template<int C>
__global__ void bnrelu_kernel(const short* __restrict__ x, const float* __restrict__ A,
                              const float* __restrict__ B, short* __restrict__ out, int N) {
    constexpr int CPR = C / 8;
    int i = blockIdx.x * 256 + threadIdx.x;
    if (i >= N * CPR) return;
    int r = i / CPR, ch = i - r * CPR;
    short8 v = *(const short8*)(x + (ll)r * C + ch * 8);
    short8 o;
    #pragma unroll
    for (int j = 0; j < 8; ++j) {
        int c = ch * 8 + j;
        float y = fmaf(bf2f(v[j]), A[c], B[c]);
        o[j] = f2bf(y > 0.f ? y : 0.f);
    }
    *(short8*)(out + (ll)r * C + ch * 8) = o;
}

__global__ void outk_kernel(const short* __restrict__ z, const float* __restrict__ A,
                            const float* __restrict__ B, const float* __restrict__ Wout,
                            float* __restrict__ out, int N) {
    __shared__ float w[64], sa[32], sb[32];
    if (threadIdx.x < 64) w[threadIdx.x] = Wout[threadIdx.x];
    if (threadIdx.x < 32) { sa[threadIdx.x] = A[threadIdx.x]; sb[threadIdx.x] = B[threadIdx.x]; }
    __syncthreads();
    int r = blockIdx.x * 256 + threadIdx.x;
    if (r >= N) return;
    const short* zp = z + (ll)r * 32;
    float o0 = 0.f, o1 = 0.f;
    #pragma unroll
    for (int s4 = 0; s4 < 4; ++s4) {
        short8 v = *(const short8*)(zp + s4 * 8);
        #pragma unroll
        for (int j = 0; j < 8; ++j) {
            int c = s4 * 8 + j;
            float y = fmaf(bf2f(v[j]), sa[c], sb[c]);
            y = y > 0.f ? y : 0.f;
            o0 = fmaf(y, w[2*c], o0);
            o1 = fmaf(y, w[2*c+1], o1);
        }
    }
    out[(ll)r * 2]     = o0;
    out[(ll)r * 2 + 1] = o1;
}

extern "C" void kernel_launch(void* const* d_in, const int* in_sizes, int n_in,
                              void* d_out, int out_size, void* d_ws, size_t ws_size,
                              hipStream_t stream) {
    const float* feats = (const float*)d_in[0];
    const float* W1 = (const float*)d_in[1];
    const float* W2 = (const float*)d_in[2];
    const float* W3 = (const float*)d_in[3];
    const float* W4 = (const float*)d_in[4];
    const float* W5 = (const float*)d_in[5];
    const float* Wout = (const float*)d_in[6];
    const float* g1 = (const float*)d_in[7],  *b1 = (const float*)d_in[8];
    const float* g2 = (const float*)d_in[9],  *b2 = (const float*)d_in[10];
    const float* g3 = (const float*)d_in[11], *b3 = (const float*)d_in[12];
    const float* g4 = (const float*)d_in[13], *b4 = (const float*)d_in[14];
    const float* g5 = (const float*)d_in[15], *b5 = (const float*)d_in[16];
    const int* nbr0 = (const int*)d_in[17];
    const int* nbr1 = (const int*)d_in[18];
    const int* nbr2 = (const int*)d_in[19];
    const int* up1_idx = (const int*)d_in[20];
    const int* up1_off = (const int*)d_in[21];
    const int* up0_idx = (const int*)d_in[22];
    const int* up0_off = (const int*)d_in[23];

    const int N0 = in_sizes[0] / 2;
    const int N1 = in_sizes[20];
    const int N2 = in_sizes[19] / 27;

    char* cur = (char*)d_ws;
    auto alloc = [&](size_t bytes) { char* p = cur; cur += (bytes + 255) & ~255ULL; return p; };
    auto cdiv = [](ll a, ll b) { return (int)((a + b - 1) / b); };

    float* stats = (float*)alloc(4096);
    float* A1 = stats,       *B1c = stats + 32;
    float* A2 = stats + 64,  *B2c = stats + 128;
    float* A3 = stats + 192, *B3c = stats + 320;
    float* A4 = stats + 448, *B4c = stats + 512;
    float* A5 = stats + 576, *B5c = stats + 608;
    short* zrow  = (short*)((char*)stats + 2560);   // 256 bf16 zeros
    int*   cnt4  = (int*)((char*)stats + 3072);
    int*   cur4  = (int*)((char*)stats + 3104);
    int*   cnt5  = (int*)((char*)stats + 3136);
    int*   cur5  = (int*)((char*)stats + 3168);
    int*   bas4  = (int*)((char*)stats + 3200);
    int*   bas5  = (int*)((char*)stats + 3264);

    float* part = (float*)alloc(2 * 1024 * 1024);

    short* z1  = (short*)alloc((size_t)N0 * 32 * 2);
    short* e1b = (short*)alloc((size_t)N0 * 32 * 2);
    short* z2  = (short*)alloc((size_t)N1 * 64 * 2);
    short* e2b = (short*)alloc((size_t)N1 * 64 * 2);
    short* z3  = (short*)alloc((size_t)N2 * 128 * 2);
    short* z4  = (short*)alloc((size_t)N1 * 64 * 2);
    short* z5  = (short*)alloc((size_t)N0 * 32 * 2);
    short* W1t = (short*)alloc(32 * 64 * 2);
    short* W2t = (short*)alloc((size_t)28 * 64 * 32 * 2);
    short* W3t = (short*)alloc((size_t)28 * 128 * 64 * 2);
    short* W4t = (short*)alloc((size_t)8 * 64 * 128 * 2);
    short* W5t = (short*)alloc((size_t)8 * 32 * 64 * 2);

    const int gridL4 = cdiv((ll)N1 + 512, 64);
    const int gridL5 = cdiv((ll)N0 + 512, 64);
    int* perm4 = (int*)alloc((size_t)gridL4 * 64 * 4);
    int* kofb4 = (int*)alloc((size_t)gridL4 * 4);
    int* perm5 = (int*)alloc((size_t)gridL5 * 64 * 4);
    int* kofb5 = (int*)alloc((size_t)gridL5 * 4);

    const int zoff1 = (int)((ll)((char*)zrow - (char*)e1b));
    const int zoff2 = (int)((ll)((char*)zrow - (char*)e2b));

    const int nblk1 = cdiv(N0, 64);
    const int nblk2 = cdiv(N1, 128);
    const int nblk3 = cdiv(N2, 128);     // L3: RG=2, 128-row blocks (R13 config)

    hipMemsetAsync((char*)stats + 2560, 0, 640, stream);   // zrow + counters

    prep_kernel<<<cdiv(2048 + 28*2048 + 28*8192 + 65536 + 16384, 256), 256, 0, stream>>>(
        W1, W2, W3, W4, W5, W1t, W2t, W3t, W4t, W5t);

    {
        int gx = cdiv(N1 > N0 ? N1 : N0, 256);
        dcountB_kernel<<<dim3(gx, 2), 256, 0, stream>>>(up1_off, N1, cnt4, up0_off, N0, cnt5);
        dprefixB_kernel<<<2, 256, 0, stream>>>(cnt4, bas4, kofb4, perm4, gridL4,
                                               cnt5, bas5, kofb5, perm5, gridL5);
        dscatterB_kernel<<<dim3(gx, 2), 256, 0, stream>>>(up1_off, bas4, cur4, perm4, N1,
                                                          up0_off, bas5, cur5, perm5, N0);
    }

    // L1: conv(2->32) -> z1; BN coeffs; bnrelu -> e1b
    c1_kernel<<<nblk1, 256, 0, stream>>>(feats, nbr0, W1t, z1, part, N0);
    red2_kernel<<<32, 256, 0, stream>>>(part, nblk1, g1, b1, A1, B1c, 32, N0);
    bnrelu_kernel<32><<<cdiv((ll)N0 * 4, 256), 256, 0, stream>>>(z1, A1, B1c, e1b, N0);

    // L2: conv(32->64), BARRIER-FREE all-weights-LDS
    msL2full_kernel<<<nblk2, 256, 0, stream>>>(e1b, nbr1, W2t, z2, part, N1, zoff1);
    red2_kernel<<<64, 256, 0, stream>>>(part, nblk2, g2, b2, A2, B2c, 64, N1);
    bnrelu_kernel<64><<<cdiv((ll)N1 * 8, 256), 256, 0, stream>>>(z2, A2, B2c, e2b, N1);

    // L3: conv(64->128), R13-verified RG=2 config -> z3 (raw)
    msconv7_kernel<64, 128, 2, 3><<<nblk3, 256, 0, stream>>>(e2b, nbr2, W3t, z3, part, N2, zoff2);
    red2_kernel<<<128, 256, 0, stream>>>(part, nblk3, g3, b3, A3, B3c, 128, N2);

    // L4: upconv(128->64), inline BN(A3,B3) -> z4 (raw)
    gdec_kernel<128, 64><<<gridL4, 256, 0, stream>>>(z3, perm4, kofb4, up1_idx, W4t, A3, B3c, z4, part);
    red2_kernel<<<64, 256, 0, stream>>>(part, gridL4, g4, b4, A4, B4c, 64, N1);

    // L5: upconv(64->32), inline BN(A4,B4) -> z5 (raw)
    gdec_kernel<64, 32><<<gridL5, 256, 0, stream>>>(z4, perm5, kofb5, up0_idx, W5t, A4, B4c, z5, part);
    red2_kernel<<<32, 256, 0, stream>>>(part, gridL5, g5, b5, A5, B5c, 32, N0);

    // out: fused BN(A5,B5)+ReLU+1x1
    outk_kernel<<<cdiv(N0, 256), 256, 0, stream>>>(z5, A5, B5c, Wout, (float*)d_out, N0);
}

// Round 17
// 234.456 us; speedup vs baseline: 1.1015x; 1.1015x over previous
//
#include <hip/hip_runtime.h>
#include <hip/hip_bf16.h>

typedef __attribute__((ext_vector_type(4))) float  f32x4;
typedef __attribute__((ext_vector_type(8))) short  short8;
typedef __attribute__((ext_vector_type(2))) float  flt2;
typedef long long ll;

__device__ __forceinline__ short f2bf(float f) {
    __hip_bfloat16 h = __float2bfloat16(f);
    short s; __builtin_memcpy(&s, &h, 2);
    return s;
}
__device__ __forceinline__ float bf2f(short s) {
    unsigned u = ((unsigned)(unsigned short)s) << 16;
    float f; __builtin_memcpy(&f, &u, 4);
    return f;
}
__device__ __forceinline__ void gload_lds16(const void* g, void* l) {
    __builtin_amdgcn_global_load_lds(
        (const __attribute__((address_space(1))) unsigned*)(g),
        (__attribute__((address_space(3))) unsigned*)(l),
        16, 0, 0);
}
// bijective XCD swizzle (m204)
__device__ __forceinline__ int xcd_swz(int bid, int nwg) {
    int q8 = nwg >> 3, r8 = nwg & 7;
    int xcd = bid & 7, j = bid >> 3;
    return (xcd < r8 ? xcd * (q8 + 1) : r8 * (q8 + 1) + (xcd - r8) * q8) + j;
}

// ---------------------------------------------------------------------------
// prep: weights -> bf16 [k][co][ci]; W2t/W3t padded to 28 k-tiles (tile 27 = 0)
// ---------------------------------------------------------------------------
__global__ void prep_kernel(const float* __restrict__ W1, const float* __restrict__ W2,
                            const float* __restrict__ W3, const float* __restrict__ W4,
                            const float* __restrict__ W5,
                            short* W1t, short* W2t, short* W3t, short* W4t, short* W5t) {
    int gid = blockIdx.x * 256 + threadIdx.x;
    if (gid < 32 * 64) {
        int co = gid >> 6, e = gid & 63;
        float v = 0.f;
        if (e < 54) { int k = e >> 1, ci = e & 1; v = W1[(k * 2 + ci) * 32 + co]; }
        W1t[gid] = f2bf(v);
        return;
    }
    int g = gid - 32 * 64;
    if (g < 28 * 2048) { int k = g / 2048, r = g % 2048, co = r >> 5, ci = r & 31;
        W2t[g] = (k < 27) ? f2bf(W2[((ll)k * 32 + ci) * 64 + co]) : (short)0; return; }
    g -= 28 * 2048;
    if (g < 28 * 8192) { int k = g / 8192, r = g % 8192, co = r >> 6, ci = r & 63;
        W3t[g] = (k < 27) ? f2bf(W3[((ll)k * 64 + ci) * 128 + co]) : (short)0; return; }
    g -= 28 * 8192;
    if (g < 8 * 64 * 128) { int k = g / (64*128), r = g % (64*128), co = r >> 7, ci = r & 127;
        W4t[g] = f2bf(W4[((ll)k * 128 + ci) * 64 + co]); return; }
    g -= 8 * 64 * 128;
    if (g < 8 * 32 * 64) { int k = g / (32*64), r = g % (32*64), co = r >> 6, ci = r & 63;
        W5t[g] = f2bf(W5[((ll)k * 64 + ci) * 32 + co]); return; }
}

// ---------------------------------------------------------------------------
// conv1 as dense MFMA GEMM + fused stats partials
// ---------------------------------------------------------------------------
__launch_bounds__(256)
__global__ void c1_kernel(const float* __restrict__ feats, const int* __restrict__ nbr,
                          const short* __restrict__ W1t, short* __restrict__ out,
                          float* __restrict__ part, int N) {
    __shared__ float sc[8 * 32];
    const int wgid = xcd_swz(blockIdx.x, gridDim.x);
    int tid = threadIdx.x, lane = tid & 63, wave = tid >> 6;
    int rb = wgid * 64 + wave * 16;
    int r = rb + (lane & 15);
    int rl = r < N ? r : N - 1;
    int seg = lane >> 4, l15 = lane & 15;
    f32x4 acc[2];
    acc[0] = (f32x4){0,0,0,0}; acc[1] = (f32x4){0,0,0,0};
    short8 a[2];
    #pragma unroll
    for (int kc = 0; kc < 2; ++kc) {
        #pragma unroll
        for (int j = 0; j < 4; ++j) {
            int k = kc * 16 + seg * 4 + j;
            flt2 f = (flt2){0.f, 0.f};
            if (k < 27) {
                int idx = nbr[(ll)k * N + rl];
                if (idx >= 0) f = *(const flt2*)(feats + 2 * (ll)idx);
            }
            a[kc][2*j]   = f2bf(f[0]);
            a[kc][2*j+1] = f2bf(f[1]);
        }
    }
    #pragma unroll
    for (int kc = 0; kc < 2; ++kc)
        #pragma unroll
        for (int c = 0; c < 2; ++c) {
            short8 b = *(const short8*)(W1t + (c*16 + l15) * 64 + kc * 32 + seg * 8);
            acc[c] = __builtin_amdgcn_mfma_f32_16x16x32_bf16(a[kc], b, acc[c], 0, 0, 0);
        }
    int r0 = rb + seg * 4;
    #pragma unroll
    for (int c = 0; c < 2; ++c) {
        int col = c * 16 + l15;
        #pragma unroll
        for (int j = 0; j < 4; ++j)
            if (r0 + j < N) out[(ll)(r0 + j) * 32 + col] = f2bf(acc[c][j]);
    }
    float s[2], q[2];
    #pragma unroll
    for (int c = 0; c < 2; ++c) { s[c] = 0.f; q[c] = 0.f; }
    #pragma unroll
    for (int c = 0; c < 2; ++c)
        #pragma unroll
        for (int j = 0; j < 4; ++j) {
            float v = (r0 + j < N) ? acc[c][j] : 0.f;
            s[c] += v; q[c] += v * v;
        }
    #pragma unroll
    for (int c = 0; c < 2; ++c) {
        s[c] += __shfl_xor(s[c], 16); q[c] += __shfl_xor(q[c], 16);
        s[c] += __shfl_xor(s[c], 32); q[c] += __shfl_xor(q[c], 32);
    }
    if (lane < 16) {
        #pragma unroll
        for (int c = 0; c < 2; ++c) {
            sc[(wave * 2 + 0) * 32 + c * 16 + l15] = s[c];
            sc[(wave * 2 + 1) * 32 + c * 16 + l15] = q[c];
        }
    }
    __syncthreads();
    for (int i = tid; i < 32; i += 256) {
        float ss = sc[0*32+i] + sc[2*32+i] + sc[4*32+i] + sc[6*32+i];
        float qq = sc[1*32+i] + sc[3*32+i] + sc[5*32+i] + sc[7*32+i];
        part[(ll)wgid * 64 + i]      = ss;
        part[(ll)wgid * 64 + 32 + i] = qq;
    }
}

// ---------------------------------------------------------------------------
// Sparse MFMA conv v7 (R13-verified): depth-1 per-k staging, pinned counted
// vmcnt, rolling scalar idx pipeline, fused stats, XCD swizzle.
// ---------------------------------------------------------------------------
template<int CIN, int COLS, int RG, int MINW>
__launch_bounds__(256, MINW)
__global__ void msconv7_kernel(const short* __restrict__ inb, const int* __restrict__ nbr,
                               const short* __restrict__ Wt, short* __restrict__ out,
                               float* __restrict__ part, int N, int zoff) {
    constexpr int KC = CIN / 32, NT = COLS / 16;
    constexpr int CPK = COLS * CIN / 8, BIT = CPK / 256;
    constexpr int WST = COLS * CIN;
    constexpr int SH = (CIN == 32) ? 6 : 7;
    __shared__ __align__(16) short lb[2][WST];

    const int wgid = xcd_swz(blockIdx.x, gridDim.x);
    const int tid = threadIdx.x, lane = tid & 63, wave = tid >> 6;
    const int seg = lane >> 4, l15 = lane & 15;
    const int wrb = wgid * (64 * RG) + wave * (16 * RG);
    const char* inB = (const char*)inb;

    int rl[RG];
    #pragma unroll
    for (int rg = 0; rg < RG; ++rg) {
        int r = wrb + rg * 16 + l15;
        rl[rg] = r < N ? r : N - 1;
    }

    auto rawIdx = [&](int k, int (&ix)[RG]) {
        #pragma unroll
        for (int rg = 0; rg < RG; ++rg) ix[rg] = nbr[(ll)k * N + rl[rg]];
    };
    auto mkoff = [&](const int (&ix)[RG], int (&o)[RG]) {
        #pragma unroll
        for (int rg = 0; rg < RG; ++rg) o[rg] = (ix[rg] >= 0) ? (ix[rg] << SH) : zoff;
    };
    auto stage = [&](int kn, int buf) {
        #pragma unroll
        for (int it = 0; it < BIT; ++it) {
            int q = it * 256 + tid;
            int co = q % COLS, sg = (q / COLS) & 3, kc = q / (COLS * 4);
            gload_lds16(Wt + (ll)kn * WST + co * CIN + kc * 32 + sg * 8, &lb[buf][q * 8]);
        }
    };
    auto ldA = [&](short8 (&a)[RG][KC], const int (&o)[RG]) {
        #pragma unroll
        for (int rg = 0; rg < RG; ++rg) {
            const char* base = inB + o[rg];
            #pragma unroll
            for (int kc = 0; kc < KC; ++kc)
                a[rg][kc] = *(const short8*)(base + kc * 64 + seg * 16);
        }
    };

    f32x4 acc[RG][NT];
    #pragma unroll
    for (int rg = 0; rg < RG; ++rg)
        #pragma unroll
        for (int c = 0; c < NT; ++c) acc[rg][c] = (f32x4){0.f, 0.f, 0.f, 0.f};

    auto compute = [&](int buf, short8 (&a)[RG][KC]) {
        #pragma unroll
        for (int kc = 0; kc < KC; ++kc)
            #pragma unroll
            for (int c = 0; c < NT; ++c) {
                short8 b = *(const short8*)&lb[buf][((kc * 4 + seg) * COLS + c * 16 + l15) * 8];
                #pragma unroll
                for (int rg = 0; rg < RG; ++rg)
                    acc[rg][c] = __builtin_amdgcn_mfma_f32_16x16x32_bf16(
                        a[rg][kc], b, acc[rg][c], 0, 0, 0);
            }
    };

    short8 aA[RG][KC], aB[RG][KC];
    int iF[RG], offC[RG];

    {
        int i0[RG], i1[RG], o0[RG];
        rawIdx(0, i0); rawIdx(1, i1); rawIdx(2, iF);
        mkoff(i0, o0); mkoff(i1, offC);
        stage(0, 0);
        __builtin_amdgcn_sched_barrier(0);
        ldA(aA, o0);
        __builtin_amdgcn_sched_barrier(0);
        asm volatile("s_waitcnt vmcnt(%0) lgkmcnt(0)" :: "n"(RG * KC) : "memory");
        __builtin_amdgcn_s_barrier();
        __builtin_amdgcn_sched_barrier(0);
    }

    #pragma unroll
    for (int k = 0; k < 27; ++k) {
        int iN[RG];
        if (k + 1 < 27) {
            if (k + 3 < 27) rawIdx(k + 3, iN);
            __builtin_amdgcn_sched_barrier(0);
            stage(k + 1, (k + 1) & 1);
            __builtin_amdgcn_sched_barrier(0);
            if (k & 1) ldA(aA, offC); else ldA(aB, offC);
            __builtin_amdgcn_sched_barrier(0);
        }
        if (k & 1) compute(1, aB); else compute(0, aA);
        if (k + 1 < 27) {
            __builtin_amdgcn_sched_barrier(0);
            asm volatile("s_waitcnt vmcnt(%0) lgkmcnt(0)" :: "n"(RG * KC) : "memory");
            __builtin_amdgcn_s_barrier();
            __builtin_amdgcn_sched_barrier(0);
            mkoff(iF, offC);
            if (k + 3 < 27) {
                #pragma unroll
                for (int rg = 0; rg < RG; ++rg) iF[rg] = iN[rg];
            }
        }
    }

    #pragma unroll
    for (int rg = 0; rg < RG; ++rg)
        #pragma unroll
        for (int c = 0; c < NT; ++c) {
            int col = c * 16 + l15;
            #pragma unroll
            for (int j = 0; j < 4; ++j) {
                int rr = wrb + rg * 16 + seg * 4 + j;
                if (rr < N) out[(ll)rr * COLS + col] = f2bf(acc[rg][c][j]);
            }
        }

    float s[NT], q[NT];
    #pragma unroll
    for (int c = 0; c < NT; ++c) { s[c] = 0.f; q[c] = 0.f; }
    #pragma unroll
    for (int rg = 0; rg < RG; ++rg)
        #pragma unroll
        for (int c = 0; c < NT; ++c)
            #pragma unroll
            for (int j = 0; j < 4; ++j) {
                int rr = wrb + rg * 16 + seg * 4 + j;
                float v = (rr < N) ? acc[rg][c][j] : 0.f;
                s[c] += v; q[c] += v * v;
            }
    #pragma unroll
    for (int c = 0; c < NT; ++c) {
        s[c] += __shfl_xor(s[c], 16); q[c] += __shfl_xor(q[c], 16);
        s[c] += __shfl_xor(s[c], 32); q[c] += __shfl_xor(q[c], 32);
    }
    __syncthreads();
    float* sc = (float*)&lb[0][0];
    if (lane < 16) {
        #pragma unroll
        for (int c = 0; c < NT; ++c) {
            sc[(wave * 2 + 0) * COLS + c * 16 + l15] = s[c];
            sc[(wave * 2 + 1) * COLS + c * 16 + l15] = q[c];
        }
    }
    __syncthreads();
    for (int i = tid; i < COLS; i += 256) {
        float ss = sc[0*COLS+i] + sc[2*COLS+i] + sc[4*COLS+i] + sc[6*COLS+i];
        float qq = sc[1*COLS+i] + sc[3*COLS+i] + sc[5*COLS+i] + sc[7*COLS+i];
        part[(ll)wgid * 2 * COLS + i]        = ss;
        part[(ll)wgid * 2 * COLS + COLS + i] = qq;
    }
}

// ---------------------------------------------------------------------------
// Decoder list build (merged)
// ---------------------------------------------------------------------------
__global__ void dcountB_kernel(const int* __restrict__ poffA, int NA, int* __restrict__ cntA,
                               const int* __restrict__ poffB, int NB, int* __restrict__ cntB) {
    const int* poff = blockIdx.y ? poffB : poffA;
    int* cnt = blockIdx.y ? cntB : cntA;
    int N = blockIdx.y ? NB : NA;
    __shared__ int lc[8];
    if (threadIdx.x < 8) lc[threadIdx.x] = 0;
    __syncthreads();
    int r = blockIdx.x * 256 + threadIdx.x;
    if (r < N) atomicAdd(&lc[poff[r]], 1);
    __syncthreads();
    if (threadIdx.x < 8 && lc[threadIdx.x]) atomicAdd(&cnt[threadIdx.x], lc[threadIdx.x]);
}

__global__ void dprefixB_kernel(const int* __restrict__ cntA, int* basesA, int* kofbA,
                                int* permA, int nblkA,
                                const int* __restrict__ cntB, int* basesB, int* kofbB,
                                int* permB, int nblkB) {
    const int* cnt = blockIdx.x ? cntB : cntA;
    int* bases = blockIdx.x ? basesB : basesA;
    int* kofb  = blockIdx.x ? kofbB  : kofbA;
    int* perm  = blockIdx.x ? permB  : permA;
    int nblk   = blockIdx.x ? nblkB  : nblkA;
    __shared__ int base[9];
    if (threadIdx.x == 0) {
        int b = 0;
        for (int k = 0; k < 8; ++k) { base[k] = b; b += (cnt[k] + 63) & ~63; }
        base[8] = b;
        for (int k = 0; k < 9; ++k) bases[k] = base[k];
    }
    __syncthreads();
    int nb = base[8] >> 6;
    for (int i = threadIdx.x; i < nblk; i += 256) {
        int k = -1;
        if (i < nb) {
            int rb = i << 6; k = 0;
            while (rb >= base[k + 1]) ++k;
        }
        kofb[i] = k;
    }
    for (int k = 0; k < 8; ++k) {
        int s = base[k] + cnt[k], e = base[k + 1];
        for (int i = s + threadIdx.x; i < e; i += 256) perm[i] = -1;
    }
}

__global__ void dscatterB_kernel(const int* __restrict__ poffA, const int* basesA,
                                 int* curA, int* permA, int NA,
                                 const int* __restrict__ poffB, const int* basesB,
                                 int* curB, int* permB, int NB) {
    const int* poff = blockIdx.y ? poffB : poffA;
    const int* bases = blockIdx.y ? basesB : basesA;
    int* curp = blockIdx.y ? curB : curA;
    int* perm = blockIdx.y ? permB : permA;
    int N = blockIdx.y ? NB : NA;
    __shared__ int lc[8], lbs[8];
    if (threadIdx.x < 8) lc[threadIdx.x] = 0;
    __syncthreads();
    int r = blockIdx.x * 256 + threadIdx.x;
    int k = 0, myl = 0;
    if (r < N) { k = poff[r]; myl = atomicAdd(&lc[k], 1); }
    __syncthreads();
    if (threadIdx.x < 8) lbs[threadIdx.x] = atomicAdd(&curp[threadIdx.x], lc[threadIdx.x]);
    __syncthreads();
    if (r < N) perm[bases[k] + lbs[k] + myl] = r;
}

// ---------------------------------------------------------------------------
// Decoder gather-GEMM: inline BN+ReLU (once/row, prologue) + stats + swizzle
// ---------------------------------------------------------------------------
template<int CIN, int COUT>
__launch_bounds__(256)
__global__ void gdec_kernel(const short* __restrict__ inb, const int* __restrict__ perm,
                            const int* __restrict__ kofb, const int* __restrict__ pidx,
                            const short* __restrict__ Wt,
                            const float* __restrict__ Abn, const float* __restrict__ Bbn,
                            short* __restrict__ out, float* __restrict__ part) {
    constexpr int KC = CIN / 32, NT = COUT / 16;
    constexpr int CPK = COUT * CIN / 8, BIT = CPK / 256;
    __shared__ __align__(16) short lb[COUT * CIN];
    const int wgid = xcd_swz(blockIdx.x, gridDim.x);
    const int tid = threadIdx.x, lane = tid & 63, wave = tid >> 6;
    int k = kofb[wgid];
    if (k < 0) {
        for (int i = tid; i < 2 * COUT; i += 256) part[(ll)wgid * 2 * COUT + i] = 0.f;
        return;
    }
    const int seg = lane >> 4, l15 = lane & 15;
    const int wrb = wgid * 64 + wave * 16;
    int rl = wrb + l15;
    int pr = perm[rl];
    int idx = pr < 0 ? -1 : pidx[pr];
    int valid = (idx >= 0);

    #pragma unroll
    for (int it = 0; it < BIT; ++it) {
        int q = it * 256 + tid;
        int co = q % COUT, sg = (q / COUT) & 3, kc = q / (COUT * 4);
        gload_lds16(Wt + ((ll)k * COUT + co) * CIN + kc * 32 + sg * 8, &lb[q * 8]);
    }
    f32x4 cA[KC][2], cB[KC][2];
    #pragma unroll
    for (int kc = 0; kc < KC; ++kc) {
        cA[kc][0] = *(const f32x4*)(Abn + kc * 32 + seg * 8);
        cA[kc][1] = *(const f32x4*)(Abn + kc * 32 + seg * 8 + 4);
        cB[kc][0] = *(const f32x4*)(Bbn + kc * 32 + seg * 8);
        cB[kc][1] = *(const f32x4*)(Bbn + kc * 32 + seg * 8 + 4);
    }
    short8 a[KC];
    const short* base = inb + (ll)(idx < 0 ? 0 : idx) * CIN;
    #pragma unroll
    for (int kc = 0; kc < KC; ++kc) {
        short8 raw = *(const short8*)(base + kc * 32 + seg * 8);
        #pragma unroll
        for (int j = 0; j < 8; ++j) {
            float x = bf2f(raw[j]);
            float y = fmaf(x, cA[kc][j >> 2][j & 3], cB[kc][j >> 2][j & 3]);
            y = y > 0.f ? y : 0.f;
            a[kc][j] = valid ? f2bf(y) : (short)0;
        }
    }

    f32x4 acc[NT];
    #pragma unroll
    for (int c = 0; c < NT; ++c) acc[c] = (f32x4){0.f, 0.f, 0.f, 0.f};
    __syncthreads();
    #pragma unroll
    for (int kc = 0; kc < KC; ++kc)
        #pragma unroll
        for (int c = 0; c < NT; ++c) {
            short8 b = *(const short8*)&lb[((kc * 4 + seg) * COUT + c * 16 + l15) * 8];
            acc[c] = __builtin_amdgcn_mfma_f32_16x16x32_bf16(a[kc], b, acc[c], 0, 0, 0);
        }
    #pragma unroll
    for (int j = 0; j < 4; ++j) {
        int prs = __shfl(pr, seg * 4 + j, 64);
        if (prs >= 0) {
            #pragma unroll
            for (int c = 0; c < NT; ++c)
                out[(ll)prs * COUT + c * 16 + l15] = f2bf(acc[c][j]);
        }
    }
    float s[NT], q[NT];
    #pragma unroll
    for (int c = 0; c < NT; ++c) { s[c] = 0.f; q[c] = 0.f; }
    #pragma unroll
    for (int c = 0; c < NT; ++c)
        #pragma unroll
        for (int j = 0; j < 4; ++j) { float v = acc[c][j]; s[c] += v; q[c] += v * v; }
    #pragma unroll
    for (int c = 0; c < NT; ++c) {
        s[c] += __shfl_xor(s[c], 16); q[c] += __shfl_xor(q[c], 16);
        s[c] += __shfl_xor(s[c], 32); q[c] += __shfl_xor(q[c], 32);
    }
    __syncthreads();
    float* sc = (float*)lb;
    if (lane < 16) {
        #pragma unroll
        for (int c = 0; c < NT; ++c) {
            sc[(wave * 2 + 0) * COUT + c * 16 + l15] = s[c];
            sc[(wave * 2 + 1) * COUT + c * 16 + l15] = q[c];
        }
    }
    __syncthreads();
    for (int i = tid; i < COUT; i += 256) {
        float ss = sc[0*COUT+i] + sc[2*COUT+i] + sc[4*COUT+i] + sc[6*COUT+i];
        float qq = sc[1*COUT+i] + sc[3*COUT+i] + sc[5*COUT+i] + sc[7*COUT+i];
        part[(ll)wgid * 2 * COUT + i]        = ss;
        part[(ll)wgid * 2 * COUT + COUT + i] = qq;
    }
}

// ---------------------------------------------------------------------------
// red2 / bnrelu / outk
// ---------------------------------------------------------------------------
__global__ void red2_kernel(const float* __restrict__ part, int nblk,
                            const float* __restrict__ g, const float* __restrict__ bb,
                            float* __restrict__ A, float* __restrict__ B, int C, int N) {
    int c = blockIdx.x;
    float s = 0.f, q = 0.f;
    for (int i = threadIdx.x; i < nblk; i += 256) {
        s += part[(ll)i * 2 * C + c];
        q += part[(ll)i * 2 * C + C + c];
    }
    __shared__ float ls[256], lq[256];
    ls[threadIdx.x] = s; lq[threadIdx.x] = q;
    __syncthreads();
    for (int str = 128; str >= 1; str >>= 1) {
        if (threadIdx.x < str) {
            ls[threadIdx.x] += ls[threadIdx.x + str];
            lq[threadIdx.x] += lq[threadIdx.x + str];
        }
        __syncthreads();
    }
    if (threadIdx.x == 0) {
        float inv = 1.0f / (float)N;
        float mu = ls[0] * inv, var = lq[0] * inv - mu * mu;
        float a = g[c] * rsqrtf(var + 1e-5f);
        A[c] = a; B[c] = bb[c] - mu * a;
    }
}

template<int C>
__global__ void bnrelu_kernel(const short* __restrict__ x, const float* __restrict__ A,
                              const float* __restrict__ B, short* __restrict__ out, int N) {
    constexpr int CPR = C / 8;
    int i = blockIdx.x * 256 + threadIdx.x;
    if (i >= N * CPR) return;
    int r = i / CPR, ch = i - r * CPR;
    short8 v = *(const short8*)(x + (ll)r * C + ch * 8);
    short8 o;
    #pragma unroll
    for (int j = 0; j < 8; ++j) {
        int c = ch * 8 + j;
        float y = fmaf(bf2f(v[j]), A[c], B[c]);
        o[j] = f2bf(y > 0.f ? y : 0.f);
    }
    *(short8*)(out + (ll)r * C + ch * 8) = o;
}

__global__ void outk_kernel(const short* __restrict__ z, const float* __restrict__ A,
                            const float* __restrict__ B, const float* __restrict__ Wout,
                            float* __restrict__ out, int N) {
    __shared__ float w[64], sa[32], sb[32];
    if (threadIdx.x < 64) w[threadIdx.x] = Wout[threadIdx.x];
    if (threadIdx.x < 32) { sa[threadIdx.x] = A[threadIdx.x]; sb[threadIdx.x] = B[threadIdx.x]; }
    __syncthreads();
    int r = blockIdx.x * 256 + threadIdx.x;
    if (r >= N) return;
    const short* zp = z + (ll)r * 32;
    float o0 = 0.f, o1 = 0.f;
    #pragma unroll
    for (int s4 = 0; s4 < 4; ++s4) {
        short8 v = *(const short8*)(zp + s4 * 8);
        #pragma unroll
        for (int j = 0; j < 8; ++j) {
            int c = s4 * 8 + j;
            float y = fmaf(bf2f(v[j]), sa[c], sb[c]);
            y = y > 0.f ? y : 0.f;
            o0 = fmaf(y, w[2*c], o0);
            o1 = fmaf(y, w[2*c+1], o1);
        }
    }
    out[(ll)r * 2]     = o0;
    out[(ll)r * 2 + 1] = o1;
}

extern "C" void kernel_launch(void* const* d_in, const int* in_sizes, int n_in,
                              void* d_out, int out_size, void* d_ws, size_t ws_size,
                              hipStream_t stream) {
    const float* feats = (const float*)d_in[0];
    const float* W1 = (const float*)d_in[1];
    const float* W2 = (const float*)d_in[2];
    const float* W3 = (const float*)d_in[3];
    const float* W4 = (const float*)d_in[4];
    const float* W5 = (const float*)d_in[5];
    const float* Wout = (const float*)d_in[6];
    const float* g1 = (const float*)d_in[7],  *b1 = (const float*)d_in[8];
    const float* g2 = (const float*)d_in[9],  *b2 = (const float*)d_in[10];
    const float* g3 = (const float*)d_in[11], *b3 = (const float*)d_in[12];
    const float* g4 = (const float*)d_in[13], *b4 = (const float*)d_in[14];
    const float* g5 = (const float*)d_in[15], *b5 = (const float*)d_in[16];
    const int* nbr0 = (const int*)d_in[17];
    const int* nbr1 = (const int*)d_in[18];
    const int* nbr2 = (const int*)d_in[19];
    const int* up1_idx = (const int*)d_in[20];
    const int* up1_off = (const int*)d_in[21];
    const int* up0_idx = (const int*)d_in[22];
    const int* up0_off = (const int*)d_in[23];

    const int N0 = in_sizes[0] / 2;
    const int N1 = in_sizes[20];
    const int N2 = in_sizes[19] / 27;

    char* cur = (char*)d_ws;
    auto alloc = [&](size_t bytes) { char* p = cur; cur += (bytes + 255) & ~255ULL; return p; };
    auto cdiv = [](ll a, ll b) { return (int)((a + b - 1) / b); };

    float* stats = (float*)alloc(4096);
    float* A1 = stats,       *B1c = stats + 32;
    float* A2 = stats + 64,  *B2c = stats + 128;
    float* A3 = stats + 192, *B3c = stats + 320;
    float* A4 = stats + 448, *B4c = stats + 512;
    float* A5 = stats + 576, *B5c = stats + 608;
    short* zrow  = (short*)((char*)stats + 2560);   // 256 bf16 zeros
    int*   cnt4  = (int*)((char*)stats + 3072);
    int*   cur4  = (int*)((char*)stats + 3104);
    int*   cnt5  = (int*)((char*)stats + 3136);
    int*   cur5  = (int*)((char*)stats + 3168);
    int*   bas4  = (int*)((char*)stats + 3200);
    int*   bas5  = (int*)((char*)stats + 3264);

    float* part = (float*)alloc(2 * 1024 * 1024);

    short* z1  = (short*)alloc((size_t)N0 * 32 * 2);
    short* e1b = (short*)alloc((size_t)N0 * 32 * 2);
    short* z2  = (short*)alloc((size_t)N1 * 64 * 2);
    short* e2b = (short*)alloc((size_t)N1 * 64 * 2);
    short* z3  = (short*)alloc((size_t)N2 * 128 * 2);
    short* z4  = (short*)alloc((size_t)N1 * 64 * 2);
    short* z5  = (short*)alloc((size_t)N0 * 32 * 2);
    short* W1t = (short*)alloc(32 * 64 * 2);
    short* W2t = (short*)alloc((size_t)28 * 64 * 32 * 2);
    short* W3t = (short*)alloc((size_t)28 * 128 * 64 * 2);
    short* W4t = (short*)alloc((size_t)8 * 64 * 128 * 2);
    short* W5t = (short*)alloc((size_t)8 * 32 * 64 * 2);

    const int gridL4 = cdiv((ll)N1 + 512, 64);
    const int gridL5 = cdiv((ll)N0 + 512, 64);
    int* perm4 = (int*)alloc((size_t)gridL4 * 64 * 4);
    int* kofb4 = (int*)alloc((size_t)gridL4 * 4);
    int* perm5 = (int*)alloc((size_t)gridL5 * 64 * 4);
    int* kofb5 = (int*)alloc((size_t)gridL5 * 4);

    const int zoff1 = (int)((ll)((char*)zrow - (char*)e1b));
    const int zoff2 = (int)((ll)((char*)zrow - (char*)e2b));

    const int nblk1 = cdiv(N0, 64);
    const int nblk2 = cdiv(N1, 128);
    const int nblk3 = cdiv(N2, 128);     // L3: RG=2, 128-row blocks (R13 config)

    hipMemsetAsync((char*)stats + 2560, 0, 640, stream);   // zrow + counters

    prep_kernel<<<cdiv(2048 + 28*2048 + 28*8192 + 65536 + 16384, 256), 256, 0, stream>>>(
        W1, W2, W3, W4, W5, W1t, W2t, W3t, W4t, W5t);

    {
        int gx = cdiv(N1 > N0 ? N1 : N0, 256);
        dcountB_kernel<<<dim3(gx, 2), 256, 0, stream>>>(up1_off, N1, cnt4, up0_off, N0, cnt5);
        dprefixB_kernel<<<2, 256, 0, stream>>>(cnt4, bas4, kofb4, perm4, gridL4,
                                               cnt5, bas5, kofb5, perm5, gridL5);
        dscatterB_kernel<<<dim3(gx, 2), 256, 0, stream>>>(up1_off, bas4, cur4, perm4, N1,
                                                          up0_off, bas5, cur5, perm5, N0);
    }

    // L1: conv(2->32) -> z1; BN coeffs; bnrelu -> e1b
    c1_kernel<<<nblk1, 256, 0, stream>>>(feats, nbr0, W1t, z1, part, N0);
    red2_kernel<<<32, 256, 0, stream>>>(part, nblk1, g1, b1, A1, B1c, 32, N0);
    bnrelu_kernel<32><<<cdiv((ll)N0 * 4, 256), 256, 0, stream>>>(z1, A1, B1c, e1b, N0);

    // L2: conv(32->64), R13-verified RG=2 config
    msconv7_kernel<32, 64, 2, 4><<<nblk2, 256, 0, stream>>>(e1b, nbr1, W2t, z2, part, N1, zoff1);
    red2_kernel<<<64, 256, 0, stream>>>(part, nblk2, g2, b2, A2, B2c, 64, N1);
    bnrelu_kernel<64><<<cdiv((ll)N1 * 8, 256), 256, 0, stream>>>(z2, A2, B2c, e2b, N1);

    // L3: conv(64->128), R13-verified RG=2 config -> z3 (raw)
    msconv7_kernel<64, 128, 2, 3><<<nblk3, 256, 0, stream>>>(e2b, nbr2, W3t, z3, part, N2, zoff2);
    red2_kernel<<<128, 256, 0, stream>>>(part, nblk3, g3, b3, A3, B3c, 128, N2);

    // L4: upconv(128->64), inline BN(A3,B3) -> z4 (raw)
    gdec_kernel<128, 64><<<gridL4, 256, 0, stream>>>(z3, perm4, kofb4, up1_idx, W4t, A3, B3c, z4, part);
    red2_kernel<<<64, 256, 0, stream>>>(part, gridL4, g4, b4, A4, B4c, 64, N1);

    // L5: upconv(64->32), inline BN(A4,B4) -> z5 (raw)
    gdec_kernel<64, 32><<<gridL5, 256, 0, stream>>>(z4, perm5, kofb5, up0_idx, W5t, A4, B4c, z5, part);
    red2_kernel<<<32, 256, 0, stream>>>(part, gridL5, g5, b5, A5, B5c, 32, N0);

    // out: fused BN(A5,B5)+ReLU+1x1
    outk_kernel<<<cdiv(N0, 256), 256, 0, stream>>>(z5, A5, B5c, Wout, (float*)d_out, N0);
}

// Round 18
// 223.679 us; speedup vs baseline: 1.1545x; 1.0482x over previous
//
#include <hip/hip_runtime.h>
#include <hip/hip_bf16.h>

typedef __attribute__((ext_vector_type(4))) float  f32x4;
typedef __attribute__((ext_vector_type(8))) short  short8;
typedef __attribute__((ext_vector_type(2))) float  flt2;
typedef long long ll;

__device__ __forceinline__ short f2bf(float f) {
    __hip_bfloat16 h = __float2bfloat16(f);
    short s; __builtin_memcpy(&s, &h, 2);
    return s;
}
__device__ __forceinline__ float bf2f(short s) {
    unsigned u = ((unsigned)(unsigned short)s) << 16;
    float f; __builtin_memcpy(&f, &u, 4);
    return f;
}
__device__ __forceinline__ void gload_lds16(const void* g, void* l) {
    __builtin_amdgcn_global_load_lds(
        (const __attribute__((address_space(1))) unsigned*)(g),
        (__attribute__((address_space(3))) unsigned*)(l),
        16, 0, 0);
}
// bijective XCD swizzle (m204)
__device__ __forceinline__ int xcd_swz(int bid, int nwg) {
    int q8 = nwg >> 3, r8 = nwg & 7;
    int xcd = bid & 7, j = bid >> 3;
    return (xcd < r8 ? xcd * (q8 + 1) : r8 * (q8 + 1) + (xcd - r8) * q8) + j;
}

// ---------------------------------------------------------------------------
// prep: weights -> bf16 [k][co][ci]; W2t/W3t padded to 28 k-tiles (tile 27 = 0)
// ---------------------------------------------------------------------------
__global__ void prep_kernel(const float* __restrict__ W1, const float* __restrict__ W2,
                            const float* __restrict__ W3, const float* __restrict__ W4,
                            const float* __restrict__ W5,
                            short* W1t, short* W2t, short* W3t, short* W4t, short* W5t) {
    int gid = blockIdx.x * 256 + threadIdx.x;
    if (gid < 32 * 64) {
        int co = gid >> 6, e = gid & 63;
        float v = 0.f;
        if (e < 54) { int k = e >> 1, ci = e & 1; v = W1[(k * 2 + ci) * 32 + co]; }
        W1t[gid] = f2bf(v);
        return;
    }
    int g = gid - 32 * 64;
    if (g < 28 * 2048) { int k = g / 2048, r = g % 2048, co = r >> 5, ci = r & 31;
        W2t[g] = (k < 27) ? f2bf(W2[((ll)k * 32 + ci) * 64 + co]) : (short)0; return; }
    g -= 28 * 2048;
    if (g < 28 * 8192) { int k = g / 8192, r = g % 8192, co = r >> 6, ci = r & 63;
        W3t[g] = (k < 27) ? f2bf(W3[((ll)k * 64 + ci) * 128 + co]) : (short)0; return; }
    g -= 28 * 8192;
    if (g < 8 * 64 * 128) { int k = g / (64*128), r = g % (64*128), co = r >> 7, ci = r & 127;
        W4t[g] = f2bf(W4[((ll)k * 128 + ci) * 64 + co]); return; }
    g -= 8 * 64 * 128;
    if (g < 8 * 32 * 64) { int k = g / (32*64), r = g % (32*64), co = r >> 6, ci = r & 63;
        W5t[g] = f2bf(W5[((ll)k * 64 + ci) * 32 + co]); return; }
}

// ---------------------------------------------------------------------------
// conv1 as dense MFMA GEMM + fused stats partials
// ---------------------------------------------------------------------------
__launch_bounds__(256)
__global__ void c1_kernel(const float* __restrict__ feats, const int* __restrict__ nbr,
                          const short* __restrict__ W1t, short* __restrict__ out,
                          float* __restrict__ part, int N) {
    __shared__ float sc[8 * 32];
    const int wgid = xcd_swz(blockIdx.x, gridDim.x);
    int tid = threadIdx.x, lane = tid & 63, wave = tid >> 6;
    int rb = wgid * 64 + wave * 16;
    int r = rb + (lane & 15);
    int rl = r < N ? r : N - 1;
    int seg = lane >> 4, l15 = lane & 15;
    f32x4 acc[2];
    acc[0] = (f32x4){0,0,0,0}; acc[1] = (f32x4){0,0,0,0};
    short8 a[2];
    #pragma unroll
    for (int kc = 0; kc < 2; ++kc) {
        #pragma unroll
        for (int j = 0; j < 4; ++j) {
            int k = kc * 16 + seg * 4 + j;
            flt2 f = (flt2){0.f, 0.f};
            if (k < 27) {
                int idx = nbr[(ll)k * N + rl];
                if (idx >= 0) f = *(const flt2*)(feats + 2 * (ll)idx);
            }
            a[kc][2*j]   = f2bf(f[0]);
            a[kc][2*j+1] = f2bf(f[1]);
        }
    }
    #pragma unroll
    for (int kc = 0; kc < 2; ++kc)
        #pragma unroll
        for (int c = 0; c < 2; ++c) {
            short8 b = *(const short8*)(W1t + (c*16 + l15) * 64 + kc * 32 + seg * 8);
            acc[c] = __builtin_amdgcn_mfma_f32_16x16x32_bf16(a[kc], b, acc[c], 0, 0, 0);
        }
    int r0 = rb + seg * 4;
    #pragma unroll
    for (int c = 0; c < 2; ++c) {
        int col = c * 16 + l15;
        #pragma unroll
        for (int j = 0; j < 4; ++j)
            if (r0 + j < N) out[(ll)(r0 + j) * 32 + col] = f2bf(acc[c][j]);
    }
    float s[2], q[2];
    #pragma unroll
    for (int c = 0; c < 2; ++c) { s[c] = 0.f; q[c] = 0.f; }
    #pragma unroll
    for (int c = 0; c < 2; ++c)
        #pragma unroll
        for (int j = 0; j < 4; ++j) {
            float v = (r0 + j < N) ? acc[c][j] : 0.f;
            s[c] += v; q[c] += v * v;
        }
    #pragma unroll
    for (int c = 0; c < 2; ++c) {
        s[c] += __shfl_xor(s[c], 16); q[c] += __shfl_xor(q[c], 16);
        s[c] += __shfl_xor(s[c], 32); q[c] += __shfl_xor(q[c], 32);
    }
    if (lane < 16) {
        #pragma unroll
        for (int c = 0; c < 2; ++c) {
            sc[(wave * 2 + 0) * 32 + c * 16 + l15] = s[c];
            sc[(wave * 2 + 1) * 32 + c * 16 + l15] = q[c];
        }
    }
    __syncthreads();
    for (int i = tid; i < 32; i += 256) {
        float ss = sc[0*32+i] + sc[2*32+i] + sc[4*32+i] + sc[6*32+i];
        float qq = sc[1*32+i] + sc[3*32+i] + sc[5*32+i] + sc[7*32+i];
        part[(ll)wgid * 64 + i]      = ss;
        part[(ll)wgid * 64 + 32 + i] = qq;
    }
}

// ---------------------------------------------------------------------------
// Sparse MFMA conv v7 (R13-verified): depth-1 per-k staging, pinned counted
// vmcnt, rolling scalar idx pipeline, fused stats, XCD swizzle.
// ---------------------------------------------------------------------------
template<int CIN, int COLS, int RG, int MINW>
__launch_bounds__(256, MINW)
__global__ void msconv7_kernel(const short* __restrict__ inb, const int* __restrict__ nbr,
                               const short* __restrict__ Wt, short* __restrict__ out,
                               float* __restrict__ part, int N, int zoff) {
    constexpr int KC = CIN / 32, NT = COLS / 16;
    constexpr int CPK = COLS * CIN / 8, BIT = CPK / 256;
    constexpr int WST = COLS * CIN;
    constexpr int SH = (CIN == 32) ? 6 : 7;
    __shared__ __align__(16) short lb[2][WST];

    const int wgid = xcd_swz(blockIdx.x, gridDim.x);
    const int tid = threadIdx.x, lane = tid & 63, wave = tid >> 6;
    const int seg = lane >> 4, l15 = lane & 15;
    const int wrb = wgid * (64 * RG) + wave * (16 * RG);
    const char* inB = (const char*)inb;

    int rl[RG];
    #pragma unroll
    for (int rg = 0; rg < RG; ++rg) {
        int r = wrb + rg * 16 + l15;
        rl[rg] = r < N ? r : N - 1;
    }

    auto rawIdx = [&](int k, int (&ix)[RG]) {
        #pragma unroll
        for (int rg = 0; rg < RG; ++rg) ix[rg] = nbr[(ll)k * N + rl[rg]];
    };
    auto mkoff = [&](const int (&ix)[RG], int (&o)[RG]) {
        #pragma unroll
        for (int rg = 0; rg < RG; ++rg) o[rg] = (ix[rg] >= 0) ? (ix[rg] << SH) : zoff;
    };
    auto stage = [&](int kn, int buf) {
        #pragma unroll
        for (int it = 0; it < BIT; ++it) {
            int q = it * 256 + tid;
            int co = q % COLS, sg = (q / COLS) & 3, kc = q / (COLS * 4);
            gload_lds16(Wt + (ll)kn * WST + co * CIN + kc * 32 + sg * 8, &lb[buf][q * 8]);
        }
    };
    auto ldA = [&](short8 (&a)[RG][KC], const int (&o)[RG]) {
        #pragma unroll
        for (int rg = 0; rg < RG; ++rg) {
            const char* base = inB + o[rg];
            #pragma unroll
            for (int kc = 0; kc < KC; ++kc)
                a[rg][kc] = *(const short8*)(base + kc * 64 + seg * 16);
        }
    };

    f32x4 acc[RG][NT];
    #pragma unroll
    for (int rg = 0; rg < RG; ++rg)
        #pragma unroll
        for (int c = 0; c < NT; ++c) acc[rg][c] = (f32x4){0.f, 0.f, 0.f, 0.f};

    auto compute = [&](int buf, short8 (&a)[RG][KC]) {
        #pragma unroll
        for (int kc = 0; kc < KC; ++kc)
            #pragma unroll
            for (int c = 0; c < NT; ++c) {
                short8 b = *(const short8*)&lb[buf][((kc * 4 + seg) * COLS + c * 16 + l15) * 8];
                #pragma unroll
                for (int rg = 0; rg < RG; ++rg)
                    acc[rg][c] = __builtin_amdgcn_mfma_f32_16x16x32_bf16(
                        a[rg][kc], b, acc[rg][c], 0, 0, 0);
            }
    };

    short8 aA[RG][KC], aB[RG][KC];
    int iF[RG], offC[RG];

    {
        int i0[RG], i1[RG], o0[RG];
        rawIdx(0, i0); rawIdx(1, i1); rawIdx(2, iF);
        mkoff(i0, o0); mkoff(i1, offC);
        stage(0, 0);
        __builtin_amdgcn_sched_barrier(0);
        ldA(aA, o0);
        __builtin_amdgcn_sched_barrier(0);
        asm volatile("s_waitcnt vmcnt(%0) lgkmcnt(0)" :: "n"(RG * KC) : "memory");
        __builtin_amdgcn_s_barrier();
        __builtin_amdgcn_sched_barrier(0);
    }

    #pragma unroll
    for (int k = 0; k < 27; ++k) {
        int iN[RG];
        if (k + 1 < 27) {
            if (k + 3 < 27) rawIdx(k + 3, iN);
            __builtin_amdgcn_sched_barrier(0);
            stage(k + 1, (k + 1) & 1);
            __builtin_amdgcn_sched_barrier(0);
            if (k & 1) ldA(aA, offC); else ldA(aB, offC);
            __builtin_amdgcn_sched_barrier(0);
        }
        if (k & 1) compute(1, aB); else compute(0, aA);
        if (k + 1 < 27) {
            __builtin_amdgcn_sched_barrier(0);
            asm volatile("s_waitcnt vmcnt(%0) lgkmcnt(0)" :: "n"(RG * KC) : "memory");
            __builtin_amdgcn_s_barrier();
            __builtin_amdgcn_sched_barrier(0);
            mkoff(iF, offC);
            if (k + 3 < 27) {
                #pragma unroll
                for (int rg = 0; rg < RG; ++rg) iF[rg] = iN[rg];
            }
        }
    }

    #pragma unroll
    for (int rg = 0; rg < RG; ++rg)
        #pragma unroll
        for (int c = 0; c < NT; ++c) {
            int col = c * 16 + l15;
            #pragma unroll
            for (int j = 0; j < 4; ++j) {
                int rr = wrb + rg * 16 + seg * 4 + j;
                if (rr < N) out[(ll)rr * COLS + col] = f2bf(acc[rg][c][j]);
            }
        }

    float s[NT], q[NT];
    #pragma unroll
    for (int c = 0; c < NT; ++c) { s[c] = 0.f; q[c] = 0.f; }
    #pragma unroll
    for (int rg = 0; rg < RG; ++rg)
        #pragma unroll
        for (int c = 0; c < NT; ++c)
            #pragma unroll
            for (int j = 0; j < 4; ++j) {
                int rr = wrb + rg * 16 + seg * 4 + j;
                float v = (rr < N) ? acc[rg][c][j] : 0.f;
                s[c] += v; q[c] += v * v;
            }
    #pragma unroll
    for (int c = 0; c < NT; ++c) {
        s[c] += __shfl_xor(s[c], 16); q[c] += __shfl_xor(q[c], 16);
        s[c] += __shfl_xor(s[c], 32); q[c] += __shfl_xor(q[c], 32);
    }
    __syncthreads();
    float* sc = (float*)&lb[0][0];
    if (lane < 16) {
        #pragma unroll
        for (int c = 0; c < NT; ++c) {
            sc[(wave * 2 + 0) * COLS + c * 16 + l15] = s[c];
            sc[(wave * 2 + 1) * COLS + c * 16 + l15] = q[c];
        }
    }
    __syncthreads();
    for (int i = tid; i < COLS; i += 256) {
        float ss = sc[0*COLS+i] + sc[2*COLS+i] + sc[4*COLS+i] + sc[6*COLS+i];
        float qq = sc[1*COLS+i] + sc[3*COLS+i] + sc[5*COLS+i] + sc[7*COLS+i];
        part[(ll)wgid * 2 * COLS + i]        = ss;
        part[(ll)wgid * 2 * COLS + COLS + i] = qq;
    }
}

// ---------------------------------------------------------------------------
// Decoder list build (merged); 128-row-padded groups (gdec RG=2)
// ---------------------------------------------------------------------------
__global__ void dcountB_kernel(const int* __restrict__ poffA, int NA, int* __restrict__ cntA,
                               const int* __restrict__ poffB, int NB, int* __restrict__ cntB) {
    const int* poff = blockIdx.y ? poffB : poffA;
    int* cnt = blockIdx.y ? cntB : cntA;
    int N = blockIdx.y ? NB : NA;
    __shared__ int lc[8];
    if (threadIdx.x < 8) lc[threadIdx.x] = 0;
    __syncthreads();
    int r = blockIdx.x * 256 + threadIdx.x;
    if (r < N) atomicAdd(&lc[poff[r]], 1);
    __syncthreads();
    if (threadIdx.x < 8 && lc[threadIdx.x]) atomicAdd(&cnt[threadIdx.x], lc[threadIdx.x]);
}

__global__ void dprefixB_kernel(const int* __restrict__ cntA, int* basesA, int* kofbA,
                                int* permA, int nblkA,
                                const int* __restrict__ cntB, int* basesB, int* kofbB,
                                int* permB, int nblkB) {
    const int* cnt = blockIdx.x ? cntB : cntA;
    int* bases = blockIdx.x ? basesB : basesA;
    int* kofb  = blockIdx.x ? kofbB  : kofbA;
    int* perm  = blockIdx.x ? permB  : permA;
    int nblk   = blockIdx.x ? nblkB  : nblkA;
    __shared__ int base[9];
    if (threadIdx.x == 0) {
        int b = 0;
        for (int k = 0; k < 8; ++k) { base[k] = b; b += (cnt[k] + 127) & ~127; }
        base[8] = b;
        for (int k = 0; k < 9; ++k) bases[k] = base[k];
    }
    __syncthreads();
    int nb = base[8] >> 7;                 // 128-row blocks
    for (int i = threadIdx.x; i < nblk; i += 256) {
        int k = -1;
        if (i < nb) {
            int rb = i << 7; k = 0;
            while (rb >= base[k + 1]) ++k;
        }
        kofb[i] = k;
    }
    for (int k = 0; k < 8; ++k) {
        int s = base[k] + cnt[k], e = base[k + 1];
        for (int i = s + threadIdx.x; i < e; i += 256) perm[i] = -1;
    }
}

__global__ void dscatterB_kernel(const int* __restrict__ poffA, const int* basesA,
                                 int* curA, int* permA, int NA,
                                 const int* __restrict__ poffB, const int* basesB,
                                 int* curB, int* permB, int NB) {
    const int* poff = blockIdx.y ? poffB : poffA;
    const int* bases = blockIdx.y ? basesB : basesA;
    int* curp = blockIdx.y ? curB : curA;
    int* perm = blockIdx.y ? permB : permA;
    int N = blockIdx.y ? NB : NA;
    __shared__ int lc[8], lbs[8];
    if (threadIdx.x < 8) lc[threadIdx.x] = 0;
    __syncthreads();
    int r = blockIdx.x * 256 + threadIdx.x;
    int k = 0, myl = 0;
    if (r < N) { k = poff[r]; myl = atomicAdd(&lc[k], 1); }
    __syncthreads();
    if (threadIdx.x < 8) lbs[threadIdx.x] = atomicAdd(&curp[threadIdx.x], lc[threadIdx.x]);
    __syncthreads();
    if (r < N) perm[bases[k] + lbs[k] + myl] = r;
}

// ---------------------------------------------------------------------------
// Decoder gather-GEMM RG=2: 128 rows/block (one staged weight tile serves
// both row-groups). Inline BN+ReLU once/row, fused stats, XCD swizzle.
// ---------------------------------------------------------------------------
template<int CIN, int COUT>
__launch_bounds__(256)
__global__ void gdec2_kernel(const short* __restrict__ inb, const int* __restrict__ perm,
                             const int* __restrict__ kofb, const int* __restrict__ pidx,
                             const short* __restrict__ Wt,
                             const float* __restrict__ Abn, const float* __restrict__ Bbn,
                             short* __restrict__ out, float* __restrict__ part) {
    constexpr int KC = CIN / 32, NT = COUT / 16;
    constexpr int CPK = COUT * CIN / 8, BIT = CPK / 256;
    __shared__ __align__(16) short lb[COUT * CIN];
    const int wgid = xcd_swz(blockIdx.x, gridDim.x);
    const int tid = threadIdx.x, lane = tid & 63, wave = tid >> 6;
    int k = kofb[wgid];
    if (k < 0) {
        for (int i = tid; i < 2 * COUT; i += 256) part[(ll)wgid * 2 * COUT + i] = 0.f;
        return;
    }
    const int seg = lane >> 4, l15 = lane & 15;
    int pr[2], idx[2], valid[2];
    #pragma unroll
    for (int g = 0; g < 2; ++g) {
        int rl = wgid * 128 + g * 64 + wave * 16 + l15;
        pr[g] = perm[rl];
        idx[g] = pr[g] < 0 ? -1 : pidx[pr[g]];
        valid[g] = (idx[g] >= 0);
    }

    #pragma unroll
    for (int it = 0; it < BIT; ++it) {
        int q = it * 256 + tid;
        int co = q % COUT, sg = (q / COUT) & 3, kc = q / (COUT * 4);
        gload_lds16(Wt + ((ll)k * COUT + co) * CIN + kc * 32 + sg * 8, &lb[q * 8]);
    }
    f32x4 cA[KC][2], cB[KC][2];
    #pragma unroll
    for (int kc = 0; kc < KC; ++kc) {
        cA[kc][0] = *(const f32x4*)(Abn + kc * 32 + seg * 8);
        cA[kc][1] = *(const f32x4*)(Abn + kc * 32 + seg * 8 + 4);
        cB[kc][0] = *(const f32x4*)(Bbn + kc * 32 + seg * 8);
        cB[kc][1] = *(const f32x4*)(Bbn + kc * 32 + seg * 8 + 4);
    }
    short8 a[2][KC];
    #pragma unroll
    for (int g = 0; g < 2; ++g) {
        const short* base = inb + (ll)(idx[g] < 0 ? 0 : idx[g]) * CIN;
        #pragma unroll
        for (int kc = 0; kc < KC; ++kc) {
            short8 raw = *(const short8*)(base + kc * 32 + seg * 8);
            #pragma unroll
            for (int j = 0; j < 8; ++j) {
                float x = bf2f(raw[j]);
                float y = fmaf(x, cA[kc][j >> 2][j & 3], cB[kc][j >> 2][j & 3]);
                y = y > 0.f ? y : 0.f;
                a[g][kc][j] = valid[g] ? f2bf(y) : (short)0;
            }
        }
    }

    f32x4 acc[2][NT];
    #pragma unroll
    for (int g = 0; g < 2; ++g)
        #pragma unroll
        for (int c = 0; c < NT; ++c) acc[g][c] = (f32x4){0.f, 0.f, 0.f, 0.f};
    __syncthreads();
    #pragma unroll
    for (int kc = 0; kc < KC; ++kc)
        #pragma unroll
        for (int c = 0; c < NT; ++c) {
            short8 b = *(const short8*)&lb[((kc * 4 + seg) * COUT + c * 16 + l15) * 8];
            #pragma unroll
            for (int g = 0; g < 2; ++g)
                acc[g][c] = __builtin_amdgcn_mfma_f32_16x16x32_bf16(a[g][kc], b, acc[g][c], 0, 0, 0);
        }
    #pragma unroll
    for (int g = 0; g < 2; ++g)
        #pragma unroll
        for (int j = 0; j < 4; ++j) {
            int prs = __shfl(pr[g], seg * 4 + j, 64);
            if (prs >= 0) {
                #pragma unroll
                for (int c = 0; c < NT; ++c)
                    out[(ll)prs * COUT + c * 16 + l15] = f2bf(acc[g][c][j]);
            }
        }
    float s[NT], q[NT];
    #pragma unroll
    for (int c = 0; c < NT; ++c) { s[c] = 0.f; q[c] = 0.f; }
    #pragma unroll
    for (int g = 0; g < 2; ++g)
        #pragma unroll
        for (int c = 0; c < NT; ++c)
            #pragma unroll
            for (int j = 0; j < 4; ++j) { float v = acc[g][c][j]; s[c] += v; q[c] += v * v; }
    #pragma unroll
    for (int c = 0; c < NT; ++c) {
        s[c] += __shfl_xor(s[c], 16); q[c] += __shfl_xor(q[c], 16);
        s[c] += __shfl_xor(s[c], 32); q[c] += __shfl_xor(q[c], 32);
    }
    __syncthreads();
    float* sc = (float*)lb;
    if (lane < 16) {
        #pragma unroll
        for (int c = 0; c < NT; ++c) {
            sc[(wave * 2 + 0) * COUT + c * 16 + l15] = s[c];
            sc[(wave * 2 + 1) * COUT + c * 16 + l15] = q[c];
        }
    }
    __syncthreads();
    for (int i = tid; i < COUT; i += 256) {
        float ss = sc[0*COUT+i] + sc[2*COUT+i] + sc[4*COUT+i] + sc[6*COUT+i];
        float qq = sc[1*COUT+i] + sc[3*COUT+i] + sc[5*COUT+i] + sc[7*COUT+i];
        part[(ll)wgid * 2 * COUT + i]        = ss;
        part[(ll)wgid * 2 * COUT + COUT + i] = qq;
    }
}

// ---------------------------------------------------------------------------
// red2 / bnrelu / outk
// ---------------------------------------------------------------------------
__global__ void red2_kernel(const float* __restrict__ part, int nblk,
                            const float* __restrict__ g, const float* __restrict__ bb,
                            float* __restrict__ A, float* __restrict__ B, int C, int N) {
    int c = blockIdx.x;
    float s = 0.f, q = 0.f;
    for (int i = threadIdx.x; i < nblk; i += 256) {
        s += part[(ll)i * 2 * C + c];
        q += part[(ll)i * 2 * C + C + c];
    }
    __shared__ float ls[256], lq[256];
    ls[threadIdx.x] = s; lq[threadIdx.x] = q;
    __syncthreads();
    for (int str = 128; str >= 1; str >>= 1) {
        if (threadIdx.x < str) {
            ls[threadIdx.x] += ls[threadIdx.x + str];
            lq[threadIdx.x] += lq[threadIdx.x + str];
        }
        __syncthreads();
    }
    if (threadIdx.x == 0) {
        float inv = 1.0f / (float)N;
        float mu = ls[0] * inv, var = lq[0] * inv - mu * mu;
        float a = g[c] * rsqrtf(var + 1e-5f);
        A[c] = a; B[c] = bb[c] - mu * a;
    }
}

template<int C>
__global__ void bnrelu_kernel(const short* __restrict__ x, const float* __restrict__ A,
                              const float* __restrict__ B, short* __restrict__ out, int N) {
    constexpr int CPR = C / 8;
    int i = blockIdx.x * 256 + threadIdx.x;
    if (i >= N * CPR) return;
    int r = i / CPR, ch = i - r * CPR;
    short8 v = *(const short8*)(x + (ll)r * C + ch * 8);
    short8 o;
    #pragma unroll
    for (int j = 0; j < 8; ++j) {
        int c = ch * 8 + j;
        float y = fmaf(bf2f(v[j]), A[c], B[c]);
        o[j] = f2bf(y > 0.f ? y : 0.f);
    }
    *(short8*)(out + (ll)r * C + ch * 8) = o;
}

__global__ void outk_kernel(const short* __restrict__ z, const float* __restrict__ A,
                            const float* __restrict__ B, const float* __restrict__ Wout,
                            float* __restrict__ out, int N) {
    __shared__ float w[64], sa[32], sb[32];
    if (threadIdx.x < 64) w[threadIdx.x] = Wout[threadIdx.x];
    if (threadIdx.x < 32) { sa[threadIdx.x] = A[threadIdx.x]; sb[threadIdx.x] = B[threadIdx.x]; }
    __syncthreads();
    int r = blockIdx.x * 256 + threadIdx.x;
    if (r >= N) return;
    const short* zp = z + (ll)r * 32;
    float o0 = 0.f, o1 = 0.f;
    #pragma unroll
    for (int s4 = 0; s4 < 4; ++s4) {
        short8 v = *(const short8*)(zp + s4 * 8);
        #pragma unroll
        for (int j = 0; j < 8; ++j) {
            int c = s4 * 8 + j;
            float y = fmaf(bf2f(v[j]), sa[c], sb[c]);
            y = y > 0.f ? y : 0.f;
            o0 = fmaf(y, w[2*c], o0);
            o1 = fmaf(y, w[2*c+1], o1);
        }
    }
    out[(ll)r * 2]     = o0;
    out[(ll)r * 2 + 1] = o1;
}

extern "C" void kernel_launch(void* const* d_in, const int* in_sizes, int n_in,
                              void* d_out, int out_size, void* d_ws, size_t ws_size,
                              hipStream_t stream) {
    const float* feats = (const float*)d_in[0];
    const float* W1 = (const float*)d_in[1];
    const float* W2 = (const float*)d_in[2];
    const float* W3 = (const float*)d_in[3];
    const float* W4 = (const float*)d_in[4];
    const float* W5 = (const float*)d_in[5];
    const float* Wout = (const float*)d_in[6];
    const float* g1 = (const float*)d_in[7],  *b1 = (const float*)d_in[8];
    const float* g2 = (const float*)d_in[9],  *b2 = (const float*)d_in[10];
    const float* g3 = (const float*)d_in[11], *b3 = (const float*)d_in[12];
    const float* g4 = (const float*)d_in[13], *b4 = (const float*)d_in[14];
    const float* g5 = (const float*)d_in[15], *b5 = (const float*)d_in[16];
    const int* nbr0 = (const int*)d_in[17];
    const int* nbr1 = (const int*)d_in[18];
    const int* nbr2 = (const int*)d_in[19];
    const int* up1_idx = (const int*)d_in[20];
    const int* up1_off = (const int*)d_in[21];
    const int* up0_idx = (const int*)d_in[22];
    const int* up0_off = (const int*)d_in[23];

    const int N0 = in_sizes[0] / 2;
    const int N1 = in_sizes[20];
    const int N2 = in_sizes[19] / 27;

    char* cur = (char*)d_ws;
    auto alloc = [&](size_t bytes) { char* p = cur; cur += (bytes + 255) & ~255ULL; return p; };
    auto cdiv = [](ll a, ll b) { return (int)((a + b - 1) / b); };

    float* stats = (float*)alloc(4096);
    float* A1 = stats,       *B1c = stats + 32;
    float* A2 = stats + 64,  *B2c = stats + 128;
    float* A3 = stats + 192, *B3c = stats + 320;
    float* A4 = stats + 448, *B4c = stats + 512;
    float* A5 = stats + 576, *B5c = stats + 608;
    short* zrow  = (short*)((char*)stats + 2560);   // 256 bf16 zeros
    int*   cnt4  = (int*)((char*)stats + 3072);
    int*   cur4  = (int*)((char*)stats + 3104);
    int*   cnt5  = (int*)((char*)stats + 3136);
    int*   cur5  = (int*)((char*)stats + 3168);
    int*   bas4  = (int*)((char*)stats + 3200);
    int*   bas5  = (int*)((char*)stats + 3264);

    float* part = (float*)alloc(2 * 1024 * 1024);

    short* z1  = (short*)alloc((size_t)N0 * 32 * 2);
    short* e1b = (short*)alloc((size_t)N0 * 32 * 2);
    short* z2  = (short*)alloc((size_t)N1 * 64 * 2);
    short* e2b = (short*)alloc((size_t)N1 * 64 * 2);
    short* z3  = (short*)alloc((size_t)N2 * 128 * 2);
    short* z4  = (short*)alloc((size_t)N1 * 64 * 2);
    short* z5  = (short*)alloc((size_t)N0 * 32 * 2);
    short* W1t = (short*)alloc(32 * 64 * 2);
    short* W2t = (short*)alloc((size_t)28 * 64 * 32 * 2);
    short* W3t = (short*)alloc((size_t)28 * 128 * 64 * 2);
    short* W4t = (short*)alloc((size_t)8 * 64 * 128 * 2);
    short* W5t = (short*)alloc((size_t)8 * 32 * 64 * 2);

    // 128-row-padded decoder groups (gdec RG=2)
    const int gridL4 = cdiv(N1, 128) + 8;
    const int gridL5 = cdiv(N0, 128) + 8;
    int* perm4 = (int*)alloc((size_t)gridL4 * 128 * 4);
    int* kofb4 = (int*)alloc((size_t)gridL4 * 4);
    int* perm5 = (int*)alloc((size_t)gridL5 * 128 * 4);
    int* kofb5 = (int*)alloc((size_t)gridL5 * 4);

    const int zoff1 = (int)((ll)((char*)zrow - (char*)e1b));
    const int zoff2 = (int)((ll)((char*)zrow - (char*)e2b));

    const int nblk1 = cdiv(N0, 64);
    const int nblk2 = cdiv(N1, 128);
    const int nblk3 = cdiv(N2, 128);

    hipMemsetAsync((char*)stats + 2560, 0, 640, stream);   // zrow + counters

    prep_kernel<<<cdiv(2048 + 28*2048 + 28*8192 + 65536 + 16384, 256), 256, 0, stream>>>(
        W1, W2, W3, W4, W5, W1t, W2t, W3t, W4t, W5t);

    {
        int gx = cdiv(N1 > N0 ? N1 : N0, 256);
        dcountB_kernel<<<dim3(gx, 2), 256, 0, stream>>>(up1_off, N1, cnt4, up0_off, N0, cnt5);
        dprefixB_kernel<<<2, 256, 0, stream>>>(cnt4, bas4, kofb4, perm4, gridL4,
                                               cnt5, bas5, kofb5, perm5, gridL5);
        dscatterB_kernel<<<dim3(gx, 2), 256, 0, stream>>>(up1_off, bas4, cur4, perm4, N1,
                                                          up0_off, bas5, cur5, perm5, N0);
    }

    // L1: conv(2->32) -> z1; BN coeffs; bnrelu -> e1b
    c1_kernel<<<nblk1, 256, 0, stream>>>(feats, nbr0, W1t, z1, part, N0);
    red2_kernel<<<32, 256, 0, stream>>>(part, nblk1, g1, b1, A1, B1c, 32, N0);
    bnrelu_kernel<32><<<cdiv((ll)N0 * 4, 256), 256, 0, stream>>>(z1, A1, B1c, e1b, N0);

    // L2: conv(32->64)
    msconv7_kernel<32, 64, 2, 4><<<nblk2, 256, 0, stream>>>(e1b, nbr1, W2t, z2, part, N1, zoff1);
    red2_kernel<<<64, 256, 0, stream>>>(part, nblk2, g2, b2, A2, B2c, 64, N1);
    bnrelu_kernel<64><<<cdiv((ll)N1 * 8, 256), 256, 0, stream>>>(z2, A2, B2c, e2b, N1);

    // L3: conv(64->128) -> z3 (raw)
    msconv7_kernel<64, 128, 2, 3><<<nblk3, 256, 0, stream>>>(e2b, nbr2, W3t, z3, part, N2, zoff2);
    red2_kernel<<<128, 256, 0, stream>>>(part, nblk3, g3, b3, A3, B3c, 128, N2);

    // L4: upconv(128->64), RG=2, inline BN(A3,B3) -> z4 (raw)
    gdec2_kernel<128, 64><<<gridL4, 256, 0, stream>>>(z3, perm4, kofb4, up1_idx, W4t, A3, B3c, z4, part);
    red2_kernel<<<64, 256, 0, stream>>>(part, gridL4, g4, b4, A4, B4c, 64, N1);

    // L5: upconv(64->32), RG=2, inline BN(A4,B4) -> z5 (raw)
    gdec2_kernel<64, 32><<<gridL5, 256, 0, stream>>>(z4, perm5, kofb5, up0_idx, W5t, A4, B4c, z5, part);
    red2_kernel<<<32, 256, 0, stream>>>(part, gridL5, g5, b5, A5, B5c, 32, N0);

    // out: fused BN(A5,B5)+ReLU+1x1
    outk_kernel<<<cdiv(N0, 256), 256, 0, stream>>>(z5, A5, B5c, Wout, (float*)d_out, N0);
}

// Round 19
// 211.984 us; speedup vs baseline: 1.2182x; 1.0552x over previous
//
#include <hip/hip_runtime.h>
#include <hip/hip_bf16.h>

typedef __attribute__((ext_vector_type(4))) float  f32x4;
typedef __attribute__((ext_vector_type(8))) short  short8;
typedef __attribute__((ext_vector_type(2))) float  flt2;
typedef long long ll;

__device__ __forceinline__ short f2bf(float f) {
    __hip_bfloat16 h = __float2bfloat16(f);
    short s; __builtin_memcpy(&s, &h, 2);
    return s;
}
__device__ __forceinline__ float bf2f(short s) {
    unsigned u = ((unsigned)(unsigned short)s) << 16;
    float f; __builtin_memcpy(&f, &u, 4);
    return f;
}
__device__ __forceinline__ void gload_lds16(const void* g, void* l) {
    __builtin_amdgcn_global_load_lds(
        (const __attribute__((address_space(1))) unsigned*)(g),
        (__attribute__((address_space(3))) unsigned*)(l),
        16, 0, 0);
}
// bijective XCD swizzle (m204)
__device__ __forceinline__ int xcd_swz(int bid, int nwg) {
    int q8 = nwg >> 3, r8 = nwg & 7;
    int xcd = bid & 7, j = bid >> 3;
    return (xcd < r8 ? xcd * (q8 + 1) : r8 * (q8 + 1) + (xcd - r8) * q8) + j;
}

// ---------------------------------------------------------------------------
// prep: weights -> bf16 [k][co][ci]; W2t/W3t padded to 28 k-tiles (tile 27 = 0)
// ---------------------------------------------------------------------------
__global__ void prep_kernel(const float* __restrict__ W1, const float* __restrict__ W2,
                            const float* __restrict__ W3, const float* __restrict__ W4,
                            const float* __restrict__ W5,
                            short* W1t, short* W2t, short* W3t, short* W4t, short* W5t) {
    int gid = blockIdx.x * 256 + threadIdx.x;
    if (gid < 32 * 64) {
        int co = gid >> 6, e = gid & 63;
        float v = 0.f;
        if (e < 54) { int k = e >> 1, ci = e & 1; v = W1[(k * 2 + ci) * 32 + co]; }
        W1t[gid] = f2bf(v);
        return;
    }
    int g = gid - 32 * 64;
    if (g < 28 * 2048) { int k = g / 2048, r = g % 2048, co = r >> 5, ci = r & 31;
        W2t[g] = (k < 27) ? f2bf(W2[((ll)k * 32 + ci) * 64 + co]) : (short)0; return; }
    g -= 28 * 2048;
    if (g < 28 * 8192) { int k = g / 8192, r = g % 8192, co = r >> 6, ci = r & 63;
        W3t[g] = (k < 27) ? f2bf(W3[((ll)k * 64 + ci) * 128 + co]) : (short)0; return; }
    g -= 28 * 8192;
    if (g < 8 * 64 * 128) { int k = g / (64*128), r = g % (64*128), co = r >> 7, ci = r & 127;
        W4t[g] = f2bf(W4[((ll)k * 128 + ci) * 64 + co]); return; }
    g -= 8 * 64 * 128;
    if (g < 8 * 32 * 64) { int k = g / (32*64), r = g % (32*64), co = r >> 6, ci = r & 63;
        W5t[g] = f2bf(W5[((ll)k * 64 + ci) * 32 + co]); return; }
}

// ---------------------------------------------------------------------------
// conv1 as dense MFMA GEMM + fused stats partials
// ---------------------------------------------------------------------------
__launch_bounds__(256)
__global__ void c1_kernel(const float* __restrict__ feats, const int* __restrict__ nbr,
                          const short* __restrict__ W1t, short* __restrict__ out,
                          float* __restrict__ part, int N) {
    __shared__ float sc[8 * 32];
    const int wgid = xcd_swz(blockIdx.x, gridDim.x);
    int tid = threadIdx.x, lane = tid & 63, wave = tid >> 6;
    int rb = wgid * 64 + wave * 16;
    int r = rb + (lane & 15);
    int rl = r < N ? r : N - 1;
    int seg = lane >> 4, l15 = lane & 15;
    f32x4 acc[2];
    acc[0] = (f32x4){0,0,0,0}; acc[1] = (f32x4){0,0,0,0};
    short8 a[2];
    #pragma unroll
    for (int kc = 0; kc < 2; ++kc) {
        #pragma unroll
        for (int j = 0; j < 4; ++j) {
            int k = kc * 16 + seg * 4 + j;
            flt2 f = (flt2){0.f, 0.f};
            if (k < 27) {
                int idx = nbr[(ll)k * N + rl];
                if (idx >= 0) f = *(const flt2*)(feats + 2 * (ll)idx);
            }
            a[kc][2*j]   = f2bf(f[0]);
            a[kc][2*j+1] = f2bf(f[1]);
        }
    }
    #pragma unroll
    for (int kc = 0; kc < 2; ++kc)
        #pragma unroll
        for (int c = 0; c < 2; ++c) {
            short8 b = *(const short8*)(W1t + (c*16 + l15) * 64 + kc * 32 + seg * 8);
            acc[c] = __builtin_amdgcn_mfma_f32_16x16x32_bf16(a[kc], b, acc[c], 0, 0, 0);
        }
    int r0 = rb + seg * 4;
    #pragma unroll
    for (int c = 0; c < 2; ++c) {
        int col = c * 16 + l15;
        #pragma unroll
        for (int j = 0; j < 4; ++j)
            if (r0 + j < N) out[(ll)(r0 + j) * 32 + col] = f2bf(acc[c][j]);
    }
    float s[2], q[2];
    #pragma unroll
    for (int c = 0; c < 2; ++c) { s[c] = 0.f; q[c] = 0.f; }
    #pragma unroll
    for (int c = 0; c < 2; ++c)
        #pragma unroll
        for (int j = 0; j < 4; ++j) {
            float v = (r0 + j < N) ? acc[c][j] : 0.f;
            s[c] += v; q[c] += v * v;
        }
    #pragma unroll
    for (int c = 0; c < 2; ++c) {
        s[c] += __shfl_xor(s[c], 16); q[c] += __shfl_xor(q[c], 16);
        s[c] += __shfl_xor(s[c], 32); q[c] += __shfl_xor(q[c], 32);
    }
    if (lane < 16) {
        #pragma unroll
        for (int c = 0; c < 2; ++c) {
            sc[(wave * 2 + 0) * 32 + c * 16 + l15] = s[c];
            sc[(wave * 2 + 1) * 32 + c * 16 + l15] = q[c];
        }
    }
    __syncthreads();
    for (int i = tid; i < 32; i += 256) {
        float ss = sc[0*32+i] + sc[2*32+i] + sc[4*32+i] + sc[6*32+i];
        float qq = sc[1*32+i] + sc[3*32+i] + sc[5*32+i] + sc[7*32+i];
        part[(ll)wgid * 64 + i]      = ss;
        part[(ll)wgid * 64 + 32 + i] = qq;
    }
}

// ---------------------------------------------------------------------------
// Sparse MFMA conv v7 (R13-verified): depth-1 per-k staging, pinned counted
// vmcnt, rolling scalar idx pipeline, fused stats, XCD swizzle.
// ---------------------------------------------------------------------------
template<int CIN, int COLS, int RG, int MINW>
__launch_bounds__(256, MINW)
__global__ void msconv7_kernel(const short* __restrict__ inb, const int* __restrict__ nbr,
                               const short* __restrict__ Wt, short* __restrict__ out,
                               float* __restrict__ part, int N, int zoff) {
    constexpr int KC = CIN / 32, NT = COLS / 16;
    constexpr int CPK = COLS * CIN / 8, BIT = CPK / 256;
    constexpr int WST = COLS * CIN;
    constexpr int SH = (CIN == 32) ? 6 : 7;
    __shared__ __align__(16) short lb[2][WST];

    const int wgid = xcd_swz(blockIdx.x, gridDim.x);
    const int tid = threadIdx.x, lane = tid & 63, wave = tid >> 6;
    const int seg = lane >> 4, l15 = lane & 15;
    const int wrb = wgid * (64 * RG) + wave * (16 * RG);
    const char* inB = (const char*)inb;

    int rl[RG];
    #pragma unroll
    for (int rg = 0; rg < RG; ++rg) {
        int r = wrb + rg * 16 + l15;
        rl[rg] = r < N ? r : N - 1;
    }

    auto rawIdx = [&](int k, int (&ix)[RG]) {
        #pragma unroll
        for (int rg = 0; rg < RG; ++rg) ix[rg] = nbr[(ll)k * N + rl[rg]];
    };
    auto mkoff = [&](const int (&ix)[RG], int (&o)[RG]) {
        #pragma unroll
        for (int rg = 0; rg < RG; ++rg) o[rg] = (ix[rg] >= 0) ? (ix[rg] << SH) : zoff;
    };
    auto stage = [&](int kn, int buf) {
        #pragma unroll
        for (int it = 0; it < BIT; ++it) {
            int q = it * 256 + tid;
            int co = q % COLS, sg = (q / COLS) & 3, kc = q / (COLS * 4);
            gload_lds16(Wt + (ll)kn * WST + co * CIN + kc * 32 + sg * 8, &lb[buf][q * 8]);
        }
    };
    auto ldA = [&](short8 (&a)[RG][KC], const int (&o)[RG]) {
        #pragma unroll
        for (int rg = 0; rg < RG; ++rg) {
            const char* base = inB + o[rg];
            #pragma unroll
            for (int kc = 0; kc < KC; ++kc)
                a[rg][kc] = *(const short8*)(base + kc * 64 + seg * 16);
        }
    };

    f32x4 acc[RG][NT];
    #pragma unroll
    for (int rg = 0; rg < RG; ++rg)
        #pragma unroll
        for (int c = 0; c < NT; ++c) acc[rg][c] = (f32x4){0.f, 0.f, 0.f, 0.f};

    auto compute = [&](int buf, short8 (&a)[RG][KC]) {
        #pragma unroll
        for (int kc = 0; kc < KC; ++kc)
            #pragma unroll
            for (int c = 0; c < NT; ++c) {
                short8 b = *(const short8*)&lb[buf][((kc * 4 + seg) * COLS + c * 16 + l15) * 8];
                #pragma unroll
                for (int rg = 0; rg < RG; ++rg)
                    acc[rg][c] = __builtin_amdgcn_mfma_f32_16x16x32_bf16(
                        a[rg][kc], b, acc[rg][c], 0, 0, 0);
            }
    };

    short8 aA[RG][KC], aB[RG][KC];
    int iF[RG], offC[RG];

    {
        int i0[RG], i1[RG], o0[RG];
        rawIdx(0, i0); rawIdx(1, i1); rawIdx(2, iF);
        mkoff(i0, o0); mkoff(i1, offC);
        stage(0, 0);
        __builtin_amdgcn_sched_barrier(0);
        ldA(aA, o0);
        __builtin_amdgcn_sched_barrier(0);
        asm volatile("s_waitcnt vmcnt(%0) lgkmcnt(0)" :: "n"(RG * KC) : "memory");
        __builtin_amdgcn_s_barrier();
        __builtin_amdgcn_sched_barrier(0);
    }

    #pragma unroll
    for (int k = 0; k < 27; ++k) {
        int iN[RG];
        if (k + 1 < 27) {
            if (k + 3 < 27) rawIdx(k + 3, iN);
            __builtin_amdgcn_sched_barrier(0);
            stage(k + 1, (k + 1) & 1);
            __builtin_amdgcn_sched_barrier(0);
            if (k & 1) ldA(aA, offC); else ldA(aB, offC);
            __builtin_amdgcn_sched_barrier(0);
        }
        if (k & 1) compute(1, aB); else compute(0, aA);
        if (k + 1 < 27) {
            __builtin_amdgcn_sched_barrier(0);
            asm volatile("s_waitcnt vmcnt(%0) lgkmcnt(0)" :: "n"(RG * KC) : "memory");
            __builtin_amdgcn_s_barrier();
            __builtin_amdgcn_sched_barrier(0);
            mkoff(iF, offC);
            if (k + 3 < 27) {
                #pragma unroll
                for (int rg = 0; rg < RG; ++rg) iF[rg] = iN[rg];
            }
        }
    }

    #pragma unroll
    for (int rg = 0; rg < RG; ++rg)
        #pragma unroll
        for (int c = 0; c < NT; ++c) {
            int col = c * 16 + l15;
            #pragma unroll
            for (int j = 0; j < 4; ++j) {
                int rr = wrb + rg * 16 + seg * 4 + j;
                if (rr < N) out[(ll)rr * COLS + col] = f2bf(acc[rg][c][j]);
            }
        }

    float s[NT], q[NT];
    #pragma unroll
    for (int c = 0; c < NT; ++c) { s[c] = 0.f; q[c] = 0.f; }
    #pragma unroll
    for (int rg = 0; rg < RG; ++rg)
        #pragma unroll
        for (int c = 0; c < NT; ++c)
            #pragma unroll
            for (int j = 0; j < 4; ++j) {
                int rr = wrb + rg * 16 + seg * 4 + j;
                float v = (rr < N) ? acc[rg][c][j] : 0.f;
                s[c] += v; q[c] += v * v;
            }
    #pragma unroll
    for (int c = 0; c < NT; ++c) {
        s[c] += __shfl_xor(s[c], 16); q[c] += __shfl_xor(q[c], 16);
        s[c] += __shfl_xor(s[c], 32); q[c] += __shfl_xor(q[c], 32);
    }
    __syncthreads();
    float* sc = (float*)&lb[0][0];
    if (lane < 16) {
        #pragma unroll
        for (int c = 0; c < NT; ++c) {
            sc[(wave * 2 + 0) * COLS + c * 16 + l15] = s[c];
            sc[(wave * 2 + 1) * COLS + c * 16 + l15] = q[c];
        }
    }
    __syncthreads();
    for (int i = tid; i < COLS; i += 256) {
        float ss = sc[0*COLS+i] + sc[2*COLS+i] + sc[4*COLS+i] + sc[6*COLS+i];
        float qq = sc[1*COLS+i] + sc[3*COLS+i] + sc[5*COLS+i] + sc[7*COLS+i];
        part[(ll)wgid * 2 * COLS + i]        = ss;
        part[(ll)wgid * 2 * COLS + COLS + i] = qq;
    }
}

// ---------------------------------------------------------------------------
// Decoder list build (merged); 128-row-padded groups (gdec RG=2)
// ---------------------------------------------------------------------------
__global__ void dcountB_kernel(const int* __restrict__ poffA, int NA, int* __restrict__ cntA,
                               const int* __restrict__ poffB, int NB, int* __restrict__ cntB) {
    const int* poff = blockIdx.y ? poffB : poffA;
    int* cnt = blockIdx.y ? cntB : cntA;
    int N = blockIdx.y ? NB : NA;
    __shared__ int lc[8];
    if (threadIdx.x < 8) lc[threadIdx.x] = 0;
    __syncthreads();
    int r = blockIdx.x * 256 + threadIdx.x;
    if (r < N) atomicAdd(&lc[poff[r]], 1);
    __syncthreads();
    if (threadIdx.x < 8 && lc[threadIdx.x]) atomicAdd(&cnt[threadIdx.x], lc[threadIdx.x]);
}

__global__ void dprefixB_kernel(const int* __restrict__ cntA, int* basesA, int* kofbA,
                                int* permA, int nblkA,
                                const int* __restrict__ cntB, int* basesB, int* kofbB,
                                int* permB, int nblkB) {
    const int* cnt = blockIdx.x ? cntB : cntA;
    int* bases = blockIdx.x ? basesB : basesA;
    int* kofb  = blockIdx.x ? kofbB  : kofbA;
    int* perm  = blockIdx.x ? permB  : permA;
    int nblk   = blockIdx.x ? nblkB  : nblkA;
    __shared__ int base[9];
    if (threadIdx.x == 0) {
        int b = 0;
        for (int k = 0; k < 8; ++k) { base[k] = b; b += (cnt[k] + 127) & ~127; }
        base[8] = b;
        for (int k = 0; k < 9; ++k) bases[k] = base[k];
    }
    __syncthreads();
    int nb = base[8] >> 7;                 // 128-row blocks
    for (int i = threadIdx.x; i < nblk; i += 256) {
        int k = -1;
        if (i < nb) {
            int rb = i << 7; k = 0;
            while (rb >= base[k + 1]) ++k;
        }
        kofb[i] = k;
    }
    for (int k = 0; k < 8; ++k) {
        int s = base[k] + cnt[k], e = base[k + 1];
        for (int i = s + threadIdx.x; i < e; i += 256) perm[i] = -1;
    }
}

__global__ void dscatterB_kernel(const int* __restrict__ poffA, const int* basesA,
                                 int* curA, int* permA, int NA,
                                 const int* __restrict__ poffB, const int* basesB,
                                 int* curB, int* permB, int NB) {
    const int* poff = blockIdx.y ? poffB : poffA;
    const int* bases = blockIdx.y ? basesB : basesA;
    int* curp = blockIdx.y ? curB : curA;
    int* perm = blockIdx.y ? permB : permA;
    int N = blockIdx.y ? NB : NA;
    __shared__ int lc[8], lbs[8];
    if (threadIdx.x < 8) lc[threadIdx.x] = 0;
    __syncthreads();
    int r = blockIdx.x * 256 + threadIdx.x;
    int k = 0, myl = 0;
    if (r < N) { k = poff[r]; myl = atomicAdd(&lc[k], 1); }
    __syncthreads();
    if (threadIdx.x < 8) lbs[threadIdx.x] = atomicAdd(&curp[threadIdx.x], lc[threadIdx.x]);
    __syncthreads();
    if (r < N) perm[bases[k] + lbs[k] + myl] = r;
}

// ---------------------------------------------------------------------------
// Decoder gather-GEMM RG=2: 128 rows/block. Inline BN+ReLU once/row, fused
// stats, XCD swizzle.
// ---------------------------------------------------------------------------
template<int CIN, int COUT>
__launch_bounds__(256)
__global__ void gdec2_kernel(const short* __restrict__ inb, const int* __restrict__ perm,
                             const int* __restrict__ kofb, const int* __restrict__ pidx,
                             const short* __restrict__ Wt,
                             const float* __restrict__ Abn, const float* __restrict__ Bbn,
                             short* __restrict__ out, float* __restrict__ part) {
    constexpr int KC = CIN / 32, NT = COUT / 16;
    constexpr int CPK = COUT * CIN / 8, BIT = CPK / 256;
    __shared__ __align__(16) short lb[COUT * CIN];
    const int wgid = xcd_swz(blockIdx.x, gridDim.x);
    const int tid = threadIdx.x, lane = tid & 63, wave = tid >> 6;
    int k = kofb[wgid];
    if (k < 0) {
        for (int i = tid; i < 2 * COUT; i += 256) part[(ll)wgid * 2 * COUT + i] = 0.f;
        return;
    }
    const int seg = lane >> 4, l15 = lane & 15;
    int pr[2], idx[2], valid[2];
    #pragma unroll
    for (int g = 0; g < 2; ++g) {
        int rl = wgid * 128 + g * 64 + wave * 16 + l15;
        pr[g] = perm[rl];
        idx[g] = pr[g] < 0 ? -1 : pidx[pr[g]];
        valid[g] = (idx[g] >= 0);
    }

    #pragma unroll
    for (int it = 0; it < BIT; ++it) {
        int q = it * 256 + tid;
        int co = q % COUT, sg = (q / COUT) & 3, kc = q / (COUT * 4);
        gload_lds16(Wt + ((ll)k * COUT + co) * CIN + kc * 32 + sg * 8, &lb[q * 8]);
    }
    f32x4 cA[KC][2], cB[KC][2];
    #pragma unroll
    for (int kc = 0; kc < KC; ++kc) {
        cA[kc][0] = *(const f32x4*)(Abn + kc * 32 + seg * 8);
        cA[kc][1] = *(const f32x4*)(Abn + kc * 32 + seg * 8 + 4);
        cB[kc][0] = *(const f32x4*)(Bbn + kc * 32 + seg * 8);
        cB[kc][1] = *(const f32x4*)(Bbn + kc * 32 + seg * 8 + 4);
    }
    short8 a[2][KC];
    #pragma unroll
    for (int g = 0; g < 2; ++g) {
        const short* base = inb + (ll)(idx[g] < 0 ? 0 : idx[g]) * CIN;
        #pragma unroll
        for (int kc = 0; kc < KC; ++kc) {
            short8 raw = *(const short8*)(base + kc * 32 + seg * 8);
            #pragma unroll
            for (int j = 0; j < 8; ++j) {
                float x = bf2f(raw[j]);
                float y = fmaf(x, cA[kc][j >> 2][j & 3], cB[kc][j >> 2][j & 3]);
                y = y > 0.f ? y : 0.f;
                a[g][kc][j] = valid[g] ? f2bf(y) : (short)0;
            }
        }
    }

    f32x4 acc[2][NT];
    #pragma unroll
    for (int g = 0; g < 2; ++g)
        #pragma unroll
        for (int c = 0; c < NT; ++c) acc[g][c] = (f32x4){0.f, 0.f, 0.f, 0.f};
    __syncthreads();
    #pragma unroll
    for (int kc = 0; kc < KC; ++kc)
        #pragma unroll
        for (int c = 0; c < NT; ++c) {
            short8 b = *(const short8*)&lb[((kc * 4 + seg) * COUT + c * 16 + l15) * 8];
            #pragma unroll
            for (int g = 0; g < 2; ++g)
                acc[g][c] = __builtin_amdgcn_mfma_f32_16x16x32_bf16(a[g][kc], b, acc[g][c], 0, 0, 0);
        }
    #pragma unroll
    for (int g = 0; g < 2; ++g)
        #pragma unroll
        for (int j = 0; j < 4; ++j) {
            int prs = __shfl(pr[g], seg * 4 + j, 64);
            if (prs >= 0) {
                #pragma unroll
                for (int c = 0; c < NT; ++c)
                    out[(ll)prs * COUT + c * 16 + l15] = f2bf(acc[g][c][j]);
            }
        }
    float s[NT], q[NT];
    #pragma unroll
    for (int c = 0; c < NT; ++c) { s[c] = 0.f; q[c] = 0.f; }
    #pragma unroll
    for (int g = 0; g < 2; ++g)
        #pragma unroll
        for (int c = 0; c < NT; ++c)
            #pragma unroll
            for (int j = 0; j < 4; ++j) { float v = acc[g][c][j]; s[c] += v; q[c] += v * v; }
    #pragma unroll
    for (int c = 0; c < NT; ++c) {
        s[c] += __shfl_xor(s[c], 16); q[c] += __shfl_xor(q[c], 16);
        s[c] += __shfl_xor(s[c], 32); q[c] += __shfl_xor(q[c], 32);
    }
    __syncthreads();
    float* sc = (float*)lb;
    if (lane < 16) {
        #pragma unroll
        for (int c = 0; c < NT; ++c) {
            sc[(wave * 2 + 0) * COUT + c * 16 + l15] = s[c];
            sc[(wave * 2 + 1) * COUT + c * 16 + l15] = q[c];
        }
    }
    __syncthreads();
    for (int i = tid; i < COUT; i += 256) {
        float ss = sc[0*COUT+i] + sc[2*COUT+i] + sc[4*COUT+i] + sc[6*COUT+i];
        float qq = sc[1*COUT+i] + sc[3*COUT+i] + sc[5*COUT+i] + sc[7*COUT+i];
        part[(ll)wgid * 2 * COUT + i]        = ss;
        part[(ll)wgid * 2 * COUT + COUT + i] = qq;
    }
}

// ---------------------------------------------------------------------------
// red2 / bnrelu / outk
// ---------------------------------------------------------------------------
__global__ void red2_kernel(const float* __restrict__ part, int nblk,
                            const float* __restrict__ g, const float* __restrict__ bb,
                            float* __restrict__ A, float* __restrict__ B, int C, int N) {
    int c = blockIdx.x;
    float s = 0.f, q = 0.f;
    for (int i = threadIdx.x; i < nblk; i += 256) {
        s += part[(ll)i * 2 * C + c];
        q += part[(ll)i * 2 * C + C + c];
    }
    __shared__ float ls[256], lq[256];
    ls[threadIdx.x] = s; lq[threadIdx.x] = q;
    __syncthreads();
    for (int str = 128; str >= 1; str >>= 1) {
        if (threadIdx.x < str) {
            ls[threadIdx.x] += ls[threadIdx.x + str];
            lq[threadIdx.x] += lq[threadIdx.x + str];
        }
        __syncthreads();
    }
    if (threadIdx.x == 0) {
        float inv = 1.0f / (float)N;
        float mu = ls[0] * inv, var = lq[0] * inv - mu * mu;
        float a = g[c] * rsqrtf(var + 1e-5f);
        A[c] = a; B[c] = bb[c] - mu * a;
    }
}

template<int C>
__global__ void bnrelu_kernel(const short* __restrict__ x, const float* __restrict__ A,
                              const float* __restrict__ B, short* __restrict__ out, int N) {
    constexpr int CPR = C / 8;
    int i = blockIdx.x * 256 + threadIdx.x;
    if (i >= N * CPR) return;
    int r = i / CPR, ch = i - r * CPR;
    short8 v = *(const short8*)(x + (ll)r * C + ch * 8);
    short8 o;
    #pragma unroll
    for (int j = 0; j < 8; ++j) {
        int c = ch * 8 + j;
        float y = fmaf(bf2f(v[j]), A[c], B[c]);
        o[j] = f2bf(y > 0.f ? y : 0.f);
    }
    *(short8*)(out + (ll)r * C + ch * 8) = o;
}

__global__ void outk_kernel(const short* __restrict__ z, const float* __restrict__ A,
                            const float* __restrict__ B, const float* __restrict__ Wout,
                            float* __restrict__ out, int N) {
    __shared__ float w[64], sa[32], sb[32];
    if (threadIdx.x < 64) w[threadIdx.x] = Wout[threadIdx.x];
    if (threadIdx.x < 32) { sa[threadIdx.x] = A[threadIdx.x]; sb[threadIdx.x] = B[threadIdx.x]; }
    __syncthreads();
    int r = blockIdx.x * 256 + threadIdx.x;
    if (r >= N) return;
    const short* zp = z + (ll)r * 32;
    float o0 = 0.f, o1 = 0.f;
    #pragma unroll
    for (int s4 = 0; s4 < 4; ++s4) {
        short8 v = *(const short8*)(zp + s4 * 8);
        #pragma unroll
        for (int j = 0; j < 8; ++j) {
            int c = s4 * 8 + j;
            float y = fmaf(bf2f(v[j]), sa[c], sb[c]);
            y = y > 0.f ? y : 0.f;
            o0 = fmaf(y, w[2*c], o0);
            o1 = fmaf(y, w[2*c+1], o1);
        }
    }
    out[(ll)r * 2]     = o0;
    out[(ll)r * 2 + 1] = o1;
}

extern "C" void kernel_launch(void* const* d_in, const int* in_sizes, int n_in,
                              void* d_out, int out_size, void* d_ws, size_t ws_size,
                              hipStream_t stream) {
    const float* feats = (const float*)d_in[0];
    const float* W1 = (const float*)d_in[1];
    const float* W2 = (const float*)d_in[2];
    const float* W3 = (const float*)d_in[3];
    const float* W4 = (const float*)d_in[4];
    const float* W5 = (const float*)d_in[5];
    const float* Wout = (const float*)d_in[6];
    const float* g1 = (const float*)d_in[7],  *b1 = (const float*)d_in[8];
    const float* g2 = (const float*)d_in[9],  *b2 = (const float*)d_in[10];
    const float* g3 = (const float*)d_in[11], *b3 = (const float*)d_in[12];
    const float* g4 = (const float*)d_in[13], *b4 = (const float*)d_in[14];
    const float* g5 = (const float*)d_in[15], *b5 = (const float*)d_in[16];
    const int* nbr0 = (const int*)d_in[17];
    const int* nbr1 = (const int*)d_in[18];
    const int* nbr2 = (const int*)d_in[19];
    const int* up1_idx = (const int*)d_in[20];
    const int* up1_off = (const int*)d_in[21];
    const int* up0_idx = (const int*)d_in[22];
    const int* up0_off = (const int*)d_in[23];

    const int N0 = in_sizes[0] / 2;
    const int N1 = in_sizes[20];
    const int N2 = in_sizes[19] / 27;

    char* cur = (char*)d_ws;
    auto alloc = [&](size_t bytes) { char* p = cur; cur += (bytes + 255) & ~255ULL; return p; };
    auto cdiv = [](ll a, ll b) { return (int)((a + b - 1) / b); };

    float* stats = (float*)alloc(4096);
    float* A1 = stats,       *B1c = stats + 32;
    float* A2 = stats + 64,  *B2c = stats + 128;
    float* A3 = stats + 192, *B3c = stats + 320;
    float* A4 = stats + 448, *B4c = stats + 512;
    float* A5 = stats + 576, *B5c = stats + 608;
    short* zrow  = (short*)((char*)stats + 2560);   // 256 bf16 zeros
    int*   cnt4  = (int*)((char*)stats + 3072);
    int*   cur4  = (int*)((char*)stats + 3104);
    int*   cnt5  = (int*)((char*)stats + 3136);
    int*   cur5  = (int*)((char*)stats + 3168);
    int*   bas4  = (int*)((char*)stats + 3200);
    int*   bas5  = (int*)((char*)stats + 3264);

    float* part = (float*)alloc(2 * 1024 * 1024);

    short* z1  = (short*)alloc((size_t)N0 * 32 * 2);
    short* e1b = (short*)alloc((size_t)N0 * 32 * 2);
    short* z2  = (short*)alloc((size_t)N1 * 64 * 2);
    short* e2b = (short*)alloc((size_t)N1 * 64 * 2);
    short* z3  = (short*)alloc((size_t)N2 * 128 * 2);
    short* z4  = (short*)alloc((size_t)N1 * 64 * 2);
    short* z5  = (short*)alloc((size_t)N0 * 32 * 2);
    short* W1t = (short*)alloc(32 * 64 * 2);
    short* W2t = (short*)alloc((size_t)28 * 64 * 32 * 2);
    short* W3t = (short*)alloc((size_t)28 * 128 * 64 * 2);
    short* W4t = (short*)alloc((size_t)8 * 64 * 128 * 2);
    short* W5t = (short*)alloc((size_t)8 * 32 * 64 * 2);

    // 128-row-padded decoder groups (gdec RG=2)
    const int gridL4 = cdiv(N1, 128) + 8;
    const int gridL5 = cdiv(N0, 128) + 8;
    int* perm4 = (int*)alloc((size_t)gridL4 * 128 * 4);
    int* kofb4 = (int*)alloc((size_t)gridL4 * 4);
    int* perm5 = (int*)alloc((size_t)gridL5 * 128 * 4);
    int* kofb5 = (int*)alloc((size_t)gridL5 * 4);

    const int zoff1 = (int)((ll)((char*)zrow - (char*)e1b));
    const int zoff2 = (int)((ll)((char*)zrow - (char*)e2b));

    const int nblk1 = cdiv(N0, 64);
    const int nblk2 = cdiv(N1, 256);     // L2: RG=4, 256-row blocks
    const int nblk3 = cdiv(N2, 128);     // L3: RG=2, 128-row blocks

    hipMemsetAsync((char*)stats + 2560, 0, 640, stream);   // zrow + counters

    prep_kernel<<<cdiv(2048 + 28*2048 + 28*8192 + 65536 + 16384, 256), 256, 0, stream>>>(
        W1, W2, W3, W4, W5, W1t, W2t, W3t, W4t, W5t);

    {
        int gx = cdiv(N1 > N0 ? N1 : N0, 256);
        dcountB_kernel<<<dim3(gx, 2), 256, 0, stream>>>(up1_off, N1, cnt4, up0_off, N0, cnt5);
        dprefixB_kernel<<<2, 256, 0, stream>>>(cnt4, bas4, kofb4, perm4, gridL4,
                                               cnt5, bas5, kofb5, perm5, gridL5);
        dscatterB_kernel<<<dim3(gx, 2), 256, 0, stream>>>(up1_off, bas4, cur4, perm4, N1,
                                                          up0_off, bas5, cur5, perm5, N0);
    }

    // L1: conv(2->32) -> z1; BN coeffs; bnrelu -> e1b
    c1_kernel<<<nblk1, 256, 0, stream>>>(feats, nbr0, W1t, z1, part, N0);
    red2_kernel<<<32, 256, 0, stream>>>(part, nblk1, g1, b1, A1, B1c, 32, N0);
    bnrelu_kernel<32><<<cdiv((ll)N0 * 4, 256), 256, 0, stream>>>(z1, A1, B1c, e1b, N0);

    // L2: conv(32->64), RG=4 (256-row blocks: staging halves vs RG=2)
    msconv7_kernel<32, 64, 4, 3><<<nblk2, 256, 0, stream>>>(e1b, nbr1, W2t, z2, part, N1, zoff1);
    red2_kernel<<<64, 256, 0, stream>>>(part, nblk2, g2, b2, A2, B2c, 64, N1);
    bnrelu_kernel<64><<<cdiv((ll)N1 * 8, 256), 256, 0, stream>>>(z2, A2, B2c, e2b, N1);

    // L3: conv(64->128), RG=2 (R13-verified) -> z3 (raw)
    msconv7_kernel<64, 128, 2, 3><<<nblk3, 256, 0, stream>>>(e2b, nbr2, W3t, z3, part, N2, zoff2);
    red2_kernel<<<128, 256, 0, stream>>>(part, nblk3, g3, b3, A3, B3c, 128, N2);

    // L4: upconv(128->64), RG=2, inline BN(A3,B3) -> z4 (raw)
    gdec2_kernel<128, 64><<<gridL4, 256, 0, stream>>>(z3, perm4, kofb4, up1_idx, W4t, A3, B3c, z4, part);
    red2_kernel<<<64, 256, 0, stream>>>(part, gridL4, g4, b4, A4, B4c, 64, N1);

    // L5: upconv(64->32), RG=2, inline BN(A4,B4) -> z5 (raw)
    gdec2_kernel<64, 32><<<gridL5, 256, 0, stream>>>(z4, perm5, kofb5, up0_idx, W5t, A4, B4c, z5, part);
    red2_kernel<<<32, 256, 0, stream>>>(part, gridL5, g5, b5, A5, B5c, 32, N0);

    // out: fused BN(A5,B5)+ReLU+1x1
    outk_kernel<<<cdiv(N0, 256), 256, 0, stream>>>(z5, A5, B5c, Wout, (float*)d_out, N0);
}

// Round 20
// 211.946 us; speedup vs baseline: 1.2185x; 1.0002x over previous
//
#include <hip/hip_runtime.h>
#include <hip/hip_bf16.h>

typedef __attribute__((ext_vector_type(4))) float  f32x4;
typedef __attribute__((ext_vector_type(8))) short  short8;
typedef __attribute__((ext_vector_type(2))) float  flt2;
typedef long long ll;

__device__ __forceinline__ short f2bf(float f) {
    __hip_bfloat16 h = __float2bfloat16(f);
    short s; __builtin_memcpy(&s, &h, 2);
    return s;
}
__device__ __forceinline__ float bf2f(short s) {
    unsigned u = ((unsigned)(unsigned short)s) << 16;
    float f; __builtin_memcpy(&f, &u, 4);
    return f;
}
__device__ __forceinline__ void gload_lds16(const void* g, void* l) {
    __builtin_amdgcn_global_load_lds(
        (const __attribute__((address_space(1))) unsigned*)(g),
        (__attribute__((address_space(3))) unsigned*)(l),
        16, 0, 0);
}
// bijective XCD swizzle (m204)
__device__ __forceinline__ int xcd_swz(int bid, int nwg) {
    int q8 = nwg >> 3, r8 = nwg & 7;
    int xcd = bid & 7, j = bid >> 3;
    return (xcd < r8 ? xcd * (q8 + 1) : r8 * (q8 + 1) + (xcd - r8) * q8) + j;
}

// ---------------------------------------------------------------------------
// prep: weights -> bf16 [k][co][ci]; W2t/W3t padded to 28 k-tiles (tile 27 = 0)
// ---------------------------------------------------------------------------
__global__ void prep_kernel(const float* __restrict__ W1, const float* __restrict__ W2,
                            const float* __restrict__ W3, const float* __restrict__ W4,
                            const float* __restrict__ W5,
                            short* W1t, short* W2t, short* W3t, short* W4t, short* W5t) {
    int gid = blockIdx.x * 256 + threadIdx.x;
    if (gid < 32 * 64) {
        int co = gid >> 6, e = gid & 63;
        float v = 0.f;
        if (e < 54) { int k = e >> 1, ci = e & 1; v = W1[(k * 2 + ci) * 32 + co]; }
        W1t[gid] = f2bf(v);
        return;
    }
    int g = gid - 32 * 64;
    if (g < 28 * 2048) { int k = g / 2048, r = g % 2048, co = r >> 5, ci = r & 31;
        W2t[g] = (k < 27) ? f2bf(W2[((ll)k * 32 + ci) * 64 + co]) : (short)0; return; }
    g -= 28 * 2048;
    if (g < 28 * 8192) { int k = g / 8192, r = g % 8192, co = r >> 6, ci = r & 63;
        W3t[g] = (k < 27) ? f2bf(W3[((ll)k * 64 + ci) * 128 + co]) : (short)0; return; }
    g -= 28 * 8192;
    if (g < 8 * 64 * 128) { int k = g / (64*128), r = g % (64*128), co = r >> 7, ci = r & 127;
        W4t[g] = f2bf(W4[((ll)k * 128 + ci) * 64 + co]); return; }
    g -= 8 * 64 * 128;
    if (g < 8 * 32 * 64) { int k = g / (32*64), r = g % (32*64), co = r >> 6, ci = r & 63;
        W5t[g] = f2bf(W5[((ll)k * 64 + ci) * 32 + co]); return; }
}

// ---------------------------------------------------------------------------
// conv1 as dense MFMA GEMM + fused stats partials
// ---------------------------------------------------------------------------
__launch_bounds__(256)
__global__ void c1_kernel(const float* __restrict__ feats, const int* __restrict__ nbr,
                          const short* __restrict__ W1t, short* __restrict__ out,
                          float* __restrict__ part, int N) {
    __shared__ float sc[8 * 32];
    const int wgid = xcd_swz(blockIdx.x, gridDim.x);
    int tid = threadIdx.x, lane = tid & 63, wave = tid >> 6;
    int rb = wgid * 64 + wave * 16;
    int r = rb + (lane & 15);
    int rl = r < N ? r : N - 1;
    int seg = lane >> 4, l15 = lane & 15;
    f32x4 acc[2];
    acc[0] = (f32x4){0,0,0,0}; acc[1] = (f32x4){0,0,0,0};
    short8 a[2];
    #pragma unroll
    for (int kc = 0; kc < 2; ++kc) {
        #pragma unroll
        for (int j = 0; j < 4; ++j) {
            int k = kc * 16 + seg * 4 + j;
            flt2 f = (flt2){0.f, 0.f};
            if (k < 27) {
                int idx = nbr[(ll)k * N + rl];
                if (idx >= 0) f = *(const flt2*)(feats + 2 * (ll)idx);
            }
            a[kc][2*j]   = f2bf(f[0]);
            a[kc][2*j+1] = f2bf(f[1]);
        }
    }
    #pragma unroll
    for (int kc = 0; kc < 2; ++kc)
        #pragma unroll
        for (int c = 0; c < 2; ++c) {
            short8 b = *(const short8*)(W1t + (c*16 + l15) * 64 + kc * 32 + seg * 8);
            acc[c] = __builtin_amdgcn_mfma_f32_16x16x32_bf16(a[kc], b, acc[c], 0, 0, 0);
        }
    int r0 = rb + seg * 4;
    #pragma unroll
    for (int c = 0; c < 2; ++c) {
        int col = c * 16 + l15;
        #pragma unroll
        for (int j = 0; j < 4; ++j)
            if (r0 + j < N) out[(ll)(r0 + j) * 32 + col] = f2bf(acc[c][j]);
    }
    float s[2], q[2];
    #pragma unroll
    for (int c = 0; c < 2; ++c) { s[c] = 0.f; q[c] = 0.f; }
    #pragma unroll
    for (int c = 0; c < 2; ++c)
        #pragma unroll
        for (int j = 0; j < 4; ++j) {
            float v = (r0 + j < N) ? acc[c][j] : 0.f;
            s[c] += v; q[c] += v * v;
        }
    #pragma unroll
    for (int c = 0; c < 2; ++c) {
        s[c] += __shfl_xor(s[c], 16); q[c] += __shfl_xor(q[c], 16);
        s[c] += __shfl_xor(s[c], 32); q[c] += __shfl_xor(q[c], 32);
    }
    if (lane < 16) {
        #pragma unroll
        for (int c = 0; c < 2; ++c) {
            sc[(wave * 2 + 0) * 32 + c * 16 + l15] = s[c];
            sc[(wave * 2 + 1) * 32 + c * 16 + l15] = q[c];
        }
    }
    __syncthreads();
    for (int i = tid; i < 32; i += 256) {
        float ss = sc[0*32+i] + sc[2*32+i] + sc[4*32+i] + sc[6*32+i];
        float qq = sc[1*32+i] + sc[3*32+i] + sc[5*32+i] + sc[7*32+i];
        part[(ll)wgid * 64 + i]      = ss;
        part[(ll)wgid * 64 + 32 + i] = qq;
    }
}

// ---------------------------------------------------------------------------
// Sparse MFMA conv v7 (generalized NW waves/block): depth-1 per-k staging,
// pinned counted vmcnt, rolling scalar idx pipeline, fused stats, XCD swz.
// Block = NW*16*RG rows x COLS. TPB = NW*64.
// ---------------------------------------------------------------------------
template<int CIN, int COLS, int RG, int NW, int MINW>
__launch_bounds__(NW * 64, MINW)
__global__ void msconv7_kernel(const short* __restrict__ inb, const int* __restrict__ nbr,
                               const short* __restrict__ Wt, short* __restrict__ out,
                               float* __restrict__ part, int N, int zoff) {
    constexpr int KC = CIN / 32, NT = COLS / 16;
    constexpr int TPB = NW * 64;
    constexpr int CPK = COLS * CIN / 8, BIT = CPK / TPB;
    constexpr int WST = COLS * CIN;
    constexpr int SH = (CIN == 32) ? 6 : 7;
    __shared__ __align__(16) short lb[2][WST];

    const int wgid = xcd_swz(blockIdx.x, gridDim.x);
    const int tid = threadIdx.x, lane = tid & 63, wave = tid >> 6;
    const int seg = lane >> 4, l15 = lane & 15;
    const int wrb = wgid * (16 * RG * NW) + wave * (16 * RG);
    const char* inB = (const char*)inb;

    int rl[RG];
    #pragma unroll
    for (int rg = 0; rg < RG; ++rg) {
        int r = wrb + rg * 16 + l15;
        rl[rg] = r < N ? r : N - 1;
    }

    auto rawIdx = [&](int k, int (&ix)[RG]) {
        #pragma unroll
        for (int rg = 0; rg < RG; ++rg) ix[rg] = nbr[(ll)k * N + rl[rg]];
    };
    auto mkoff = [&](const int (&ix)[RG], int (&o)[RG]) {
        #pragma unroll
        for (int rg = 0; rg < RG; ++rg) o[rg] = (ix[rg] >= 0) ? (ix[rg] << SH) : zoff;
    };
    auto stage = [&](int kn, int buf) {
        #pragma unroll
        for (int it = 0; it < BIT; ++it) {
            int q = it * TPB + tid;
            int co = q % COLS, sg = (q / COLS) & 3, kc = q / (COLS * 4);
            gload_lds16(Wt + (ll)kn * WST + co * CIN + kc * 32 + sg * 8, &lb[buf][q * 8]);
        }
    };
    auto ldA = [&](short8 (&a)[RG][KC], const int (&o)[RG]) {
        #pragma unroll
        for (int rg = 0; rg < RG; ++rg) {
            const char* base = inB + o[rg];
            #pragma unroll
            for (int kc = 0; kc < KC; ++kc)
                a[rg][kc] = *(const short8*)(base + kc * 64 + seg * 16);
        }
    };

    f32x4 acc[RG][NT];
    #pragma unroll
    for (int rg = 0; rg < RG; ++rg)
        #pragma unroll
        for (int c = 0; c < NT; ++c) acc[rg][c] = (f32x4){0.f, 0.f, 0.f, 0.f};

    auto compute = [&](int buf, short8 (&a)[RG][KC]) {
        #pragma unroll
        for (int kc = 0; kc < KC; ++kc)
            #pragma unroll
            for (int c = 0; c < NT; ++c) {
                short8 b = *(const short8*)&lb[buf][((kc * 4 + seg) * COLS + c * 16 + l15) * 8];
                #pragma unroll
                for (int rg = 0; rg < RG; ++rg)
                    acc[rg][c] = __builtin_amdgcn_mfma_f32_16x16x32_bf16(
                        a[rg][kc], b, acc[rg][c], 0, 0, 0);
            }
    };

    short8 aA[RG][KC], aB[RG][KC];
    int iF[RG], offC[RG];

    {
        int i0[RG], i1[RG], o0[RG];
        rawIdx(0, i0); rawIdx(1, i1); rawIdx(2, iF);
        mkoff(i0, o0); mkoff(i1, offC);
        stage(0, 0);
        __builtin_amdgcn_sched_barrier(0);
        ldA(aA, o0);
        __builtin_amdgcn_sched_barrier(0);
        asm volatile("s_waitcnt vmcnt(%0) lgkmcnt(0)" :: "n"(RG * KC) : "memory");
        __builtin_amdgcn_s_barrier();
        __builtin_amdgcn_sched_barrier(0);
    }

    #pragma unroll
    for (int k = 0; k < 27; ++k) {
        int iN[RG];
        if (k + 1 < 27) {
            if (k + 3 < 27) rawIdx(k + 3, iN);
            __builtin_amdgcn_sched_barrier(0);
            stage(k + 1, (k + 1) & 1);
            __builtin_amdgcn_sched_barrier(0);
            if (k & 1) ldA(aA, offC); else ldA(aB, offC);
            __builtin_amdgcn_sched_barrier(0);
        }
        if (k & 1) compute(1, aB); else compute(0, aA);
        if (k + 1 < 27) {
            __builtin_amdgcn_sched_barrier(0);
            asm volatile("s_waitcnt vmcnt(%0) lgkmcnt(0)" :: "n"(RG * KC) : "memory");
            __builtin_amdgcn_s_barrier();
            __builtin_amdgcn_sched_barrier(0);
            mkoff(iF, offC);
            if (k + 3 < 27) {
                #pragma unroll
                for (int rg = 0; rg < RG; ++rg) iF[rg] = iN[rg];
            }
        }
    }

    #pragma unroll
    for (int rg = 0; rg < RG; ++rg)
        #pragma unroll
        for (int c = 0; c < NT; ++c) {
            int col = c * 16 + l15;
            #pragma unroll
            for (int j = 0; j < 4; ++j) {
                int rr = wrb + rg * 16 + seg * 4 + j;
                if (rr < N) out[(ll)rr * COLS + col] = f2bf(acc[rg][c][j]);
            }
        }

    float s[NT], q[NT];
    #pragma unroll
    for (int c = 0; c < NT; ++c) { s[c] = 0.f; q[c] = 0.f; }
    #pragma unroll
    for (int rg = 0; rg < RG; ++rg)
        #pragma unroll
        for (int c = 0; c < NT; ++c)
            #pragma unroll
            for (int j = 0; j < 4; ++j) {
                int rr = wrb + rg * 16 + seg * 4 + j;
                float v = (rr < N) ? acc[rg][c][j] : 0.f;
                s[c] += v; q[c] += v * v;
            }
    #pragma unroll
    for (int c = 0; c < NT; ++c) {
        s[c] += __shfl_xor(s[c], 16); q[c] += __shfl_xor(q[c], 16);
        s[c] += __shfl_xor(s[c], 32); q[c] += __shfl_xor(q[c], 32);
    }
    __syncthreads();
    float* sc = (float*)&lb[0][0];            // NW*2*COLS floats (fits in lb)
    if (lane < 16) {
        #pragma unroll
        for (int c = 0; c < NT; ++c) {
            sc[(wave * 2 + 0) * COLS + c * 16 + l15] = s[c];
            sc[(wave * 2 + 1) * COLS + c * 16 + l15] = q[c];
        }
    }
    __syncthreads();
    for (int i = tid; i < COLS; i += TPB) {
        float ss = 0.f, qq = 0.f;
        #pragma unroll
        for (int w = 0; w < NW; ++w) {
            ss += sc[(2 * w + 0) * COLS + i];
            qq += sc[(2 * w + 1) * COLS + i];
        }
        part[(ll)wgid * 2 * COLS + i]        = ss;
        part[(ll)wgid * 2 * COLS + COLS + i] = qq;
    }
}

// ---------------------------------------------------------------------------
// Decoder list build (merged); 128-row-padded groups (gdec RG=2)
// ---------------------------------------------------------------------------
__global__ void dcountB_kernel(const int* __restrict__ poffA, int NA, int* __restrict__ cntA,
                               const int* __restrict__ poffB, int NB, int* __restrict__ cntB) {
    const int* poff = blockIdx.y ? poffB : poffA;
    int* cnt = blockIdx.y ? cntB : cntA;
    int N = blockIdx.y ? NB : NA;
    __shared__ int lc[8];
    if (threadIdx.x < 8) lc[threadIdx.x] = 0;
    __syncthreads();
    int r = blockIdx.x * 256 + threadIdx.x;
    if (r < N) atomicAdd(&lc[poff[r]], 1);
    __syncthreads();
    if (threadIdx.x < 8 && lc[threadIdx.x]) atomicAdd(&cnt[threadIdx.x], lc[threadIdx.x]);
}

__global__ void dprefixB_kernel(const int* __restrict__ cntA, int* basesA, int* kofbA,
                                int* permA, int nblkA,
                                const int* __restrict__ cntB, int* basesB, int* kofbB,
                                int* permB, int nblkB) {
    const int* cnt = blockIdx.x ? cntB : cntA;
    int* bases = blockIdx.x ? basesB : basesA;
    int* kofb  = blockIdx.x ? kofbB  : kofbA;
    int* perm  = blockIdx.x ? permB  : permA;
    int nblk   = blockIdx.x ? nblkB  : nblkA;
    __shared__ int base[9];
    if (threadIdx.x == 0) {
        int b = 0;
        for (int k = 0; k < 8; ++k) { base[k] = b; b += (cnt[k] + 127) & ~127; }
        base[8] = b;
        for (int k = 0; k < 9; ++k) bases[k] = base[k];
    }
    __syncthreads();
    int nb = base[8] >> 7;                 // 128-row blocks
    for (int i = threadIdx.x; i < nblk; i += 256) {
        int k = -1;
        if (i < nb) {
            int rb = i << 7; k = 0;
            while (rb >= base[k + 1]) ++k;
        }
        kofb[i] = k;
    }
    for (int k = 0; k < 8; ++k) {
        int s = base[k] + cnt[k], e = base[k + 1];
        for (int i = s + threadIdx.x; i < e; i += 256) perm[i] = -1;
    }
}

__global__ void dscatterB_kernel(const int* __restrict__ poffA, const int* basesA,
                                 int* curA, int* permA, int NA,
                                 const int* __restrict__ poffB, const int* basesB,
                                 int* curB, int* permB, int NB) {
    const int* poff = blockIdx.y ? poffB : poffA;
    const int* bases = blockIdx.y ? basesB : basesA;
    int* curp = blockIdx.y ? curB : curA;
    int* perm = blockIdx.y ? permB : permA;
    int N = blockIdx.y ? NB : NA;
    __shared__ int lc[8], lbs[8];
    if (threadIdx.x < 8) lc[threadIdx.x] = 0;
    __syncthreads();
    int r = blockIdx.x * 256 + threadIdx.x;
    int k = 0, myl = 0;
    if (r < N) { k = poff[r]; myl = atomicAdd(&lc[k], 1); }
    __syncthreads();
    if (threadIdx.x < 8) lbs[threadIdx.x] = atomicAdd(&curp[threadIdx.x], lc[threadIdx.x]);
    __syncthreads();
    if (r < N) perm[bases[k] + lbs[k] + myl] = r;
}

// ---------------------------------------------------------------------------
// Decoder gather-GEMM RG=2: 128 rows/block. Inline BN+ReLU once/row, fused
// stats, XCD swizzle.
// ---------------------------------------------------------------------------
template<int CIN, int COUT>
__launch_bounds__(256)
__global__ void gdec2_kernel(const short* __restrict__ inb, const int* __restrict__ perm,
                             const int* __restrict__ kofb, const int* __restrict__ pidx,
                             const short* __restrict__ Wt,
                             const float* __restrict__ Abn, const float* __restrict__ Bbn,
                             short* __restrict__ out, float* __restrict__ part) {
    constexpr int KC = CIN / 32, NT = COUT / 16;
    constexpr int CPK = COUT * CIN / 8, BIT = CPK / 256;
    __shared__ __align__(16) short lb[COUT * CIN];
    const int wgid = xcd_swz(blockIdx.x, gridDim.x);
    const int tid = threadIdx.x, lane = tid & 63, wave = tid >> 6;
    int k = kofb[wgid];
    if (k < 0) {
        for (int i = tid; i < 2 * COUT; i += 256) part[(ll)wgid * 2 * COUT + i] = 0.f;
        return;
    }
    const int seg = lane >> 4, l15 = lane & 15;
    int pr[2], idx[2], valid[2];
    #pragma unroll
    for (int g = 0; g < 2; ++g) {
        int rl = wgid * 128 + g * 64 + wave * 16 + l15;
        pr[g] = perm[rl];
        idx[g] = pr[g] < 0 ? -1 : pidx[pr[g]];
        valid[g] = (idx[g] >= 0);
    }

    #pragma unroll
    for (int it = 0; it < BIT; ++it) {
        int q = it * 256 + tid;
        int co = q % COUT, sg = (q / COUT) & 3, kc = q / (COUT * 4);
        gload_lds16(Wt + ((ll)k * COUT + co) * CIN + kc * 32 + sg * 8, &lb[q * 8]);
    }
    f32x4 cA[KC][2], cB[KC][2];
    #pragma unroll
    for (int kc = 0; kc < KC; ++kc) {
        cA[kc][0] = *(const f32x4*)(Abn + kc * 32 + seg * 8);
        cA[kc][1] = *(const f32x4*)(Abn + kc * 32 + seg * 8 + 4);
        cB[kc][0] = *(const f32x4*)(Bbn + kc * 32 + seg * 8);
        cB[kc][1] = *(const f32x4*)(Bbn + kc * 32 + seg * 8 + 4);
    }
    short8 a[2][KC];
    #pragma unroll
    for (int g = 0; g < 2; ++g) {
        const short* base = inb + (ll)(idx[g] < 0 ? 0 : idx[g]) * CIN;
        #pragma unroll
        for (int kc = 0; kc < KC; ++kc) {
            short8 raw = *(const short8*)(base + kc * 32 + seg * 8);
            #pragma unroll
            for (int j = 0; j < 8; ++j) {
                float x = bf2f(raw[j]);
                float y = fmaf(x, cA[kc][j >> 2][j & 3], cB[kc][j >> 2][j & 3]);
                y = y > 0.f ? y : 0.f;
                a[g][kc][j] = valid[g] ? f2bf(y) : (short)0;
            }
        }
    }

    f32x4 acc[2][NT];
    #pragma unroll
    for (int g = 0; g < 2; ++g)
        #pragma unroll
        for (int c = 0; c < NT; ++c) acc[g][c] = (f32x4){0.f, 0.f, 0.f, 0.f};
    __syncthreads();
    #pragma unroll
    for (int kc = 0; kc < KC; ++kc)
        #pragma unroll
        for (int c = 0; c < NT; ++c) {
            short8 b = *(const short8*)&lb[((kc * 4 + seg) * COUT + c * 16 + l15) * 8];
            #pragma unroll
            for (int g = 0; g < 2; ++g)
                acc[g][c] = __builtin_amdgcn_mfma_f32_16x16x32_bf16(a[g][kc], b, acc[g][c], 0, 0, 0);
        }
    #pragma unroll
    for (int g = 0; g < 2; ++g)
        #pragma unroll
        for (int j = 0; j < 4; ++j) {
            int prs = __shfl(pr[g], seg * 4 + j, 64);
            if (prs >= 0) {
                #pragma unroll
                for (int c = 0; c < NT; ++c)
                    out[(ll)prs * COUT + c * 16 + l15] = f2bf(acc[g][c][j]);
            }
        }
    float s[NT], q[NT];
    #pragma unroll
    for (int c = 0; c < NT; ++c) { s[c] = 0.f; q[c] = 0.f; }
    #pragma unroll
    for (int g = 0; g < 2; ++g)
        #pragma unroll
        for (int c = 0; c < NT; ++c)
            #pragma unroll
            for (int j = 0; j < 4; ++j) { float v = acc[g][c][j]; s[c] += v; q[c] += v * v; }
    #pragma unroll
    for (int c = 0; c < NT; ++c) {
        s[c] += __shfl_xor(s[c], 16); q[c] += __shfl_xor(q[c], 16);
        s[c] += __shfl_xor(s[c], 32); q[c] += __shfl_xor(q[c], 32);
    }
    __syncthreads();
    float* sc = (float*)lb;
    if (lane < 16) {
        #pragma unroll
        for (int c = 0; c < NT; ++c) {
            sc[(wave * 2 + 0) * COUT + c * 16 + l15] = s[c];
            sc[(wave * 2 + 1) * COUT + c * 16 + l15] = q[c];
        }
    }
    __syncthreads();
    for (int i = tid; i < COUT; i += 256) {
        float ss = sc[0*COUT+i] + sc[2*COUT+i] + sc[4*COUT+i] + sc[6*COUT+i];
        float qq = sc[1*COUT+i] + sc[3*COUT+i] + sc[5*COUT+i] + sc[7*COUT+i];
        part[(ll)wgid * 2 * COUT + i]        = ss;
        part[(ll)wgid * 2 * COUT + COUT + i] = qq;
    }
}

// ---------------------------------------------------------------------------
// red2 / bnrelu / outk
// ---------------------------------------------------------------------------
__global__ void red2_kernel(const float* __restrict__ part, int nblk,
                            const float* __restrict__ g, const float* __restrict__ bb,
                            float* __restrict__ A, float* __restrict__ B, int C, int N) {
    int c = blockIdx.x;
    float s = 0.f, q = 0.f;
    for (int i = threadIdx.x; i < nblk; i += 256) {
        s += part[(ll)i * 2 * C + c];
        q += part[(ll)i * 2 * C + C + c];
    }
    __shared__ float ls[256], lq[256];
    ls[threadIdx.x] = s; lq[threadIdx.x] = q;
    __syncthreads();
    for (int str = 128; str >= 1; str >>= 1) {
        if (threadIdx.x < str) {
            ls[threadIdx.x] += ls[threadIdx.x + str];
            lq[threadIdx.x] += lq[threadIdx.x + str];
        }
        __syncthreads();
    }
    if (threadIdx.x == 0) {
        float inv = 1.0f / (float)N;
        float mu = ls[0] * inv, var = lq[0] * inv - mu * mu;
        float a = g[c] * rsqrtf(var + 1e-5f);
        A[c] = a; B[c] = bb[c] - mu * a;
    }
}

template<int C>
__global__ void bnrelu_kernel(const short* __restrict__ x, const float* __restrict__ A,
                              const float* __restrict__ B, short* __restrict__ out, int N) {
    constexpr int CPR = C / 8;
    int i = blockIdx.x * 256 + threadIdx.x;
    if (i >= N * CPR) return;
    int r = i / CPR, ch = i - r * CPR;
    short8 v = *(const short8*)(x + (ll)r * C + ch * 8);
    short8 o;
    #pragma unroll
    for (int j = 0; j < 8; ++j) {
        int c = ch * 8 + j;
        float y = fmaf(bf2f(v[j]), A[c], B[c]);
        o[j] = f2bf(y > 0.f ? y : 0.f);
    }
    *(short8*)(out + (ll)r * C + ch * 8) = o;
}

__global__ void outk_kernel(const short* __restrict__ z, const float* __restrict__ A,
                            const float* __restrict__ B, const float* __restrict__ Wout,
                            float* __restrict__ out, int N) {
    __shared__ float w[64], sa[32], sb[32];
    if (threadIdx.x < 64) w[threadIdx.x] = Wout[threadIdx.x];
    if (threadIdx.x < 32) { sa[threadIdx.x] = A[threadIdx.x]; sb[threadIdx.x] = B[threadIdx.x]; }
    __syncthreads();
    int r = blockIdx.x * 256 + threadIdx.x;
    if (r >= N) return;
    const short* zp = z + (ll)r * 32;
    float o0 = 0.f, o1 = 0.f;
    #pragma unroll
    for (int s4 = 0; s4 < 4; ++s4) {
        short8 v = *(const short8*)(zp + s4 * 8);
        #pragma unroll
        for (int j = 0; j < 8; ++j) {
            int c = s4 * 8 + j;
            float y = fmaf(bf2f(v[j]), sa[c], sb[c]);
            y = y > 0.f ? y : 0.f;
            o0 = fmaf(y, w[2*c], o0);
            o1 = fmaf(y, w[2*c+1], o1);
        }
    }
    out[(ll)r * 2]     = o0;
    out[(ll)r * 2 + 1] = o1;
}

extern "C" void kernel_launch(void* const* d_in, const int* in_sizes, int n_in,
                              void* d_out, int out_size, void* d_ws, size_t ws_size,
                              hipStream_t stream) {
    const float* feats = (const float*)d_in[0];
    const float* W1 = (const float*)d_in[1];
    const float* W2 = (const float*)d_in[2];
    const float* W3 = (const float*)d_in[3];
    const float* W4 = (const float*)d_in[4];
    const float* W5 = (const float*)d_in[5];
    const float* Wout = (const float*)d_in[6];
    const float* g1 = (const float*)d_in[7],  *b1 = (const float*)d_in[8];
    const float* g2 = (const float*)d_in[9],  *b2 = (const float*)d_in[10];
    const float* g3 = (const float*)d_in[11], *b3 = (const float*)d_in[12];
    const float* g4 = (const float*)d_in[13], *b4 = (const float*)d_in[14];
    const float* g5 = (const float*)d_in[15], *b5 = (const float*)d_in[16];
    const int* nbr0 = (const int*)d_in[17];
    const int* nbr1 = (const int*)d_in[18];
    const int* nbr2 = (const int*)d_in[19];
    const int* up1_idx = (const int*)d_in[20];
    const int* up1_off = (const int*)d_in[21];
    const int* up0_idx = (const int*)d_in[22];
    const int* up0_off = (const int*)d_in[23];

    const int N0 = in_sizes[0] / 2;
    const int N1 = in_sizes[20];
    const int N2 = in_sizes[19] / 27;

    char* cur = (char*)d_ws;
    auto alloc = [&](size_t bytes) { char* p = cur; cur += (bytes + 255) & ~255ULL; return p; };
    auto cdiv = [](ll a, ll b) { return (int)((a + b - 1) / b); };

    float* stats = (float*)alloc(4096);
    float* A1 = stats,       *B1c = stats + 32;
    float* A2 = stats + 64,  *B2c = stats + 128;
    float* A3 = stats + 192, *B3c = stats + 320;
    float* A4 = stats + 448, *B4c = stats + 512;
    float* A5 = stats + 576, *B5c = stats + 608;
    short* zrow  = (short*)((char*)stats + 2560);   // 256 bf16 zeros
    int*   cnt4  = (int*)((char*)stats + 3072);
    int*   cur4  = (int*)((char*)stats + 3104);
    int*   cnt5  = (int*)((char*)stats + 3136);
    int*   cur5  = (int*)((char*)stats + 3168);
    int*   bas4  = (int*)((char*)stats + 3200);
    int*   bas5  = (int*)((char*)stats + 3264);

    float* part = (float*)alloc(2 * 1024 * 1024);

    short* z1  = (short*)alloc((size_t)N0 * 32 * 2);
    short* e1b = (short*)alloc((size_t)N0 * 32 * 2);
    short* z2  = (short*)alloc((size_t)N1 * 64 * 2);
    short* e2b = (short*)alloc((size_t)N1 * 64 * 2);
    short* z3  = (short*)alloc((size_t)N2 * 128 * 2);
    short* z4  = (short*)alloc((size_t)N1 * 64 * 2);
    short* z5  = (short*)alloc((size_t)N0 * 32 * 2);
    short* W1t = (short*)alloc(32 * 64 * 2);
    short* W2t = (short*)alloc((size_t)28 * 64 * 32 * 2);
    short* W3t = (short*)alloc((size_t)28 * 128 * 64 * 2);
    short* W4t = (short*)alloc((size_t)8 * 64 * 128 * 2);
    short* W5t = (short*)alloc((size_t)8 * 32 * 64 * 2);

    // 128-row-padded decoder groups (gdec RG=2)
    const int gridL4 = cdiv(N1, 128) + 8;
    const int gridL5 = cdiv(N0, 128) + 8;
    int* perm4 = (int*)alloc((size_t)gridL4 * 128 * 4);
    int* kofb4 = (int*)alloc((size_t)gridL4 * 4);
    int* perm5 = (int*)alloc((size_t)gridL5 * 128 * 4);
    int* kofb5 = (int*)alloc((size_t)gridL5 * 4);

    const int zoff1 = (int)((ll)((char*)zrow - (char*)e1b));
    const int zoff2 = (int)((ll)((char*)zrow - (char*)e2b));

    const int nblk1 = cdiv(N0, 64);
    const int nblk2 = cdiv(N1, 256);     // L2: RG=4, NW=4, 256-row blocks
    const int nblk3 = cdiv(N2, 128);     // L3: RG=1, NW=8, 128-row blocks

    hipMemsetAsync((char*)stats + 2560, 0, 640, stream);   // zrow + counters

    prep_kernel<<<cdiv(2048 + 28*2048 + 28*8192 + 65536 + 16384, 256), 256, 0, stream>>>(
        W1, W2, W3, W4, W5, W1t, W2t, W3t, W4t, W5t);

    {
        int gx = cdiv(N1 > N0 ? N1 : N0, 256);
        dcountB_kernel<<<dim3(gx, 2), 256, 0, stream>>>(up1_off, N1, cnt4, up0_off, N0, cnt5);
        dprefixB_kernel<<<2, 256, 0, stream>>>(cnt4, bas4, kofb4, perm4, gridL4,
                                               cnt5, bas5, kofb5, perm5, gridL5);
        dscatterB_kernel<<<dim3(gx, 2), 256, 0, stream>>>(up1_off, bas4, cur4, perm4, N1,
                                                          up0_off, bas5, cur5, perm5, N0);
    }

    // L1: conv(2->32) -> z1; BN coeffs; bnrelu -> e1b
    c1_kernel<<<nblk1, 256, 0, stream>>>(feats, nbr0, W1t, z1, part, N0);
    red2_kernel<<<32, 256, 0, stream>>>(part, nblk1, g1, b1, A1, B1c, 32, N0);
    bnrelu_kernel<32><<<cdiv((ll)N0 * 4, 256), 256, 0, stream>>>(z1, A1, B1c, e1b, N0);

    // L2: conv(32->64), RG=4, NW=4 (R19-verified)
    msconv7_kernel<32, 64, 4, 4, 3><<<nblk2, 256, 0, stream>>>(e1b, nbr1, W2t, z2, part, N1, zoff1);
    red2_kernel<<<64, 256, 0, stream>>>(part, nblk2, g2, b2, A2, B2c, 64, N1);
    bnrelu_kernel<64><<<cdiv((ll)N1 * 8, 256), 256, 0, stream>>>(z2, A2, B2c, e2b, N1);

    // L3: conv(64->128), NW=8 (512 thr, 2x waves/CU, same tile/staging) -> z3
    msconv7_kernel<64, 128, 1, 8, 4><<<nblk3, 512, 0, stream>>>(e2b, nbr2, W3t, z3, part, N2, zoff2);
    red2_kernel<<<128, 256, 0, stream>>>(part, nblk3, g3, b3, A3, B3c, 128, N2);

    // L4: upconv(128->64), RG=2, inline BN(A3,B3) -> z4 (raw)
    gdec2_kernel<128, 64><<<gridL4, 256, 0, stream>>>(z3, perm4, kofb4, up1_idx, W4t, A3, B3c, z4, part);
    red2_kernel<<<64, 256, 0, stream>>>(part, gridL4, g4, b4, A4, B4c, 64, N1);

    // L5: upconv(64->32), RG=2, inline BN(A4,B4) -> z5 (raw)
    gdec2_kernel<64, 32><<<gridL5, 256, 0, stream>>>(z4, perm5, kofb5, up0_idx, W5t, A4, B4c, z5, part);
    red2_kernel<<<32, 256, 0, stream>>>(part, gridL5, g5, b5, A5, B5c, 32, N0);

    // out: fused BN(A5,B5)+ReLU+1x1
    outk_kernel<<<cdiv(N0, 256), 256, 0, stream>>>(z5, A5, B5c, Wout, (float*)d_out, N0);
}